// Round 1
// baseline (4820.218 us; speedup 1.0000x reference)
//
#include <hip/hip_runtime.h>
#include <hip/hip_bf16.h>

#define B_ 4
#define S_ 4096
#define D_ 1024
#define H_ 16
#define R_ 256
#define DP_ 64
#define TS_ 32

// ============================================================
// GEMM: C[16384x1024] = A[16384x1024] @ W[1024x1024] (+bias)
// 128x128 tile, 256 threads, 8x8 per thread (2x2 blocks of 4x4)
// ============================================================
template <bool BIAS>
__device__ __forceinline__ void gemm128_body(const float* __restrict__ A,
                                             const float* __restrict__ W,
                                             float* __restrict__ C,
                                             const float* __restrict__ bias) {
  __shared__ float As[16][128];
  __shared__ float Bs[16][128];
  const int tid = threadIdx.x;
  const int tx = tid & 15;
  const int ty = tid >> 4;
  const int m0 = blockIdx.y * 128;
  const int n0 = blockIdx.x * 128;

  const int lm = tid >> 2;          // 0..63 (A row in tile, +64 second pass)
  const int lk4 = (tid & 3) << 2;   // 0,4,8,12 (A col)
  const int lkb = tid >> 4;         // 0..15 (B row)
  const int lnb = (tid & 15) << 2;  // 0..60 (B col, +64 second pass)

  float acc[8][8];
#pragma unroll
  for (int i = 0; i < 8; ++i)
#pragma unroll
    for (int j = 0; j < 8; ++j) acc[i][j] = 0.f;

  for (int k0 = 0; k0 < D_; k0 += 16) {
    const float4 a0 = *(const float4*)&A[(m0 + lm) * D_ + k0 + lk4];
    const float4 a1 = *(const float4*)&A[(m0 + lm + 64) * D_ + k0 + lk4];
    const float4 b0 = *(const float4*)&W[(k0 + lkb) * D_ + n0 + lnb];
    const float4 b1 = *(const float4*)&W[(k0 + lkb) * D_ + n0 + lnb + 64];
    __syncthreads();
    As[lk4 + 0][lm] = a0.x; As[lk4 + 1][lm] = a0.y;
    As[lk4 + 2][lm] = a0.z; As[lk4 + 3][lm] = a0.w;
    As[lk4 + 0][lm + 64] = a1.x; As[lk4 + 1][lm + 64] = a1.y;
    As[lk4 + 2][lm + 64] = a1.z; As[lk4 + 3][lm + 64] = a1.w;
    *(float4*)&Bs[lkb][lnb] = b0;
    *(float4*)&Bs[lkb][lnb + 64] = b1;
    __syncthreads();
#pragma unroll
    for (int kk = 0; kk < 16; ++kk) {
      float ar[8], br[8];
      *(float4*)&ar[0] = *(const float4*)&As[kk][ty << 2];
      *(float4*)&ar[4] = *(const float4*)&As[kk][64 + (ty << 2)];
      *(float4*)&br[0] = *(const float4*)&Bs[kk][tx << 2];
      *(float4*)&br[4] = *(const float4*)&Bs[kk][64 + (tx << 2)];
#pragma unroll
      for (int i = 0; i < 8; ++i)
#pragma unroll
        for (int j = 0; j < 8; ++j) acc[i][j] += ar[i] * br[j];
    }
  }

#pragma unroll
  for (int i = 0; i < 8; ++i) {
    const int row = m0 + ((i < 4) ? ((ty << 2) + i) : (64 + (ty << 2) + (i - 4)));
#pragma unroll
    for (int jb = 0; jb < 2; ++jb) {
      const int col = n0 + jb * 64 + (tx << 2);
      float4 v;
      v.x = acc[i][jb * 4 + 0];
      v.y = acc[i][jb * 4 + 1];
      v.z = acc[i][jb * 4 + 2];
      v.w = acc[i][jb * 4 + 3];
      if (BIAS) {
        v.x += bias[col + 0]; v.y += bias[col + 1];
        v.z += bias[col + 2]; v.w += bias[col + 3];
      }
      *(float4*)&C[row * D_ + col] = v;
    }
  }
}

__global__ __launch_bounds__(256) void qkv_gemm_kernel(
    const float* __restrict__ x, const float* __restrict__ wq,
    const float* __restrict__ wk, const float* __restrict__ wv,
    float* __restrict__ q, float* __restrict__ k, float* __restrict__ v) {
  const float* W = (blockIdx.z == 0) ? wq : (blockIdx.z == 1) ? wk : wv;
  float* C = (blockIdx.z == 0) ? q : (blockIdx.z == 1) ? k : v;
  gemm128_body<false>(x, W, C, nullptr);
}

__global__ __launch_bounds__(256) void out_gemm_kernel(
    const float* __restrict__ ao, const float* __restrict__ wo,
    const float* __restrict__ bo, float* __restrict__ out) {
  gemm128_body<true>(ao, wo, out, bo);
}

// ============================================================
// kproj/vproj: per (b,h): out[r][d] = sum_n P[h][n][r] * src[b][n][h*64+d]
// 64x64 tile (whole [R slice x DP]), 256 threads, 4x4/thread, K=4096
// grid: (R/64=4, B*H=64, 2)  z=0:(k,E)->kproj  z=1:(v,F)->vproj
// ============================================================
__global__ __launch_bounds__(256) void proj_gemm_kernel(
    const float* __restrict__ kbuf, const float* __restrict__ vbuf,
    const float* __restrict__ E, const float* __restrict__ F,
    float* __restrict__ kproj, float* __restrict__ vproj) {
  __shared__ float Es[16][64];
  __shared__ float Ks[16][64];
  const int tid = threadIdx.x;
  const int tx = tid & 15;
  const int ty = tid >> 4;
  const int bh = blockIdx.y;
  const int b = bh >> 4, h = bh & 15;
  const int r0 = blockIdx.x * 64;

  const float* src = blockIdx.z ? vbuf : kbuf;
  const float* P = blockIdx.z ? F : E;
  float* outp = blockIdx.z ? vproj : kproj;

  const float* Pbase = P + (size_t)h * S_ * R_;
  const float* src_b = src + (size_t)b * S_ * D_ + h * DP_;

  const int nl = tid >> 4;         // 0..15
  const int cl = (tid & 15) << 2;  // 0..60

  float acc[4][4];
#pragma unroll
  for (int i = 0; i < 4; ++i)
#pragma unroll
    for (int j = 0; j < 4; ++j) acc[i][j] = 0.f;

  for (int n0 = 0; n0 < S_; n0 += 16) {
    const float4 e = *(const float4*)&Pbase[(n0 + nl) * R_ + r0 + cl];
    const float4 kv = *(const float4*)&src_b[(size_t)(n0 + nl) * D_ + cl];
    __syncthreads();
    *(float4*)&Es[nl][cl] = e;
    *(float4*)&Ks[nl][cl] = kv;
    __syncthreads();
#pragma unroll
    for (int kk = 0; kk < 16; ++kk) {
      float a[4], bb[4];
      *(float4*)&a[0] = *(const float4*)&Es[kk][ty << 2];
      *(float4*)&bb[0] = *(const float4*)&Ks[kk][tx << 2];
#pragma unroll
      for (int i = 0; i < 4; ++i)
#pragma unroll
        for (int j = 0; j < 4; ++j) acc[i][j] += a[i] * bb[j];
    }
  }

#pragma unroll
  for (int i = 0; i < 4; ++i) {
    const int r = r0 + (ty << 2) + i;
    float4 v;
    v.x = acc[i][0]; v.y = acc[i][1]; v.z = acc[i][2]; v.w = acc[i][3];
    *(float4*)&outp[((size_t)bh * R_ + r) * DP_ + (tx << 2)] = v;
  }
}

// ============================================================
// Fused: scores -> conv(3,R SAME) -> softmax -> attn@vproj
// grid: (S/TS=128, B*H=64), 256 threads
// ============================================================
__global__ __launch_bounds__(256) void attn_fused_kernel(
    const float* __restrict__ qbuf, const float* __restrict__ kproj,
    const float* __restrict__ vproj, const float* __restrict__ ck,
    const float* __restrict__ cbias, float* __restrict__ ao) {
  __shared__ float S_lds[TS_ + 2][R_];  // scores, later reused for conv/attn
  __shared__ float q_lds[TS_ + 2][DP_];
  __shared__ float Kf[3][R_];

  const int tid = threadIdx.x;
  const int s0 = blockIdx.x * TS_;
  const int bh = blockIdx.y;
  const int b = bh >> 4, h = bh & 15;

  // load conv kernel (768 floats) and q rows (incl. halo)
#pragma unroll
  for (int i = 0; i < 3; ++i) Kf[i][tid] = ck[i * R_ + tid];
  for (int idx = tid; idx < (TS_ + 2) * DP_; idx += 256) {
    const int t = idx >> 6, d = idx & 63;
    const int s = s0 - 1 + t;
    float val = 0.f;
    if (s >= 0 && s < S_) val = qbuf[((size_t)(b * S_ + s)) * D_ + h * DP_ + d];
    q_lds[t][d] = val;
  }
  __syncthreads();

  // ---- phase 1: scores S[t][r] = scale * q[t] . kproj[r] ----
  {
    const int r = tid;
    float kp[64];
    const float* kpr = &kproj[((size_t)bh * R_ + r) * DP_];
#pragma unroll
    for (int d4 = 0; d4 < 64; d4 += 4) *(float4*)&kp[d4] = *(const float4*)&kpr[d4];
    for (int t = 0; t < TS_ + 2; ++t) {
      float p0 = 0.f, p1 = 0.f, p2 = 0.f, p3 = 0.f;
#pragma unroll
      for (int d = 0; d < 64; d += 4) {
        p0 += q_lds[t][d + 0] * kp[d + 0];
        p1 += q_lds[t][d + 1] * kp[d + 1];
        p2 += q_lds[t][d + 2] * kp[d + 2];
        p3 += q_lds[t][d + 3] * kp[d + 3];
      }
      S_lds[t][r] = (p0 + p1 + p2 + p3) * 0.125f;
    }
  }
  __syncthreads();

  // ---- phase 2: conv. thread -> cols {2c, 2c+1}, rows half*16..+15 ----
  float acc0[16], acc1[16];
  {
    const int c = tid & 127;
    const int half = tid >> 7;
    const float bias = cbias[0];
#pragma unroll
    for (int o = 0; o < 16; ++o) { acc0[o] = bias; acc1[o] = bias; }
    const int r0c = 2 * c;
    for (int i = 0; i < 3; ++i) {
      for (int p = -127; p <= 129; ++p) {
        const int j0 = p + 127;  // kernel idx for col r0c   (0..256)
        const int j1 = p + 126;  // kernel idx for col r0c+1 (-1..255)
        const float kf0 = (j0 <= 255) ? Kf[i][j0] : 0.f;
        const float kf1 = (j1 >= 0) ? Kf[i][j1] : 0.f;
        const int cc = r0c + p;
        if ((unsigned)cc < 256u) {
#pragma unroll
          for (int o = 0; o < 16; ++o) {
            const float sv = S_lds[half * 16 + o + i][cc];
            acc0[o] += sv * kf0;
            acc1[o] += sv * kf1;
          }
        }
      }
    }
  }
  __syncthreads();  // all conv reads of S_lds done; safe to overwrite
  {
    const int c = tid & 127;
    const int half = tid >> 7;
#pragma unroll
    for (int o = 0; o < 16; ++o) {
      S_lds[half * 16 + o][2 * c] = acc0[o];
      S_lds[half * 16 + o][2 * c + 1] = acc1[o];
    }
  }
  __syncthreads();

  // ---- phase 3: softmax over r, one row per wave-iteration ----
  {
    const int lane = tid & 63;
    const int w = tid >> 6;
    for (int ii = 0; ii < 8; ++ii) {
      const int o = w * 8 + ii;
      float v0 = S_lds[o][lane], v1 = S_lds[o][lane + 64];
      float v2 = S_lds[o][lane + 128], v3 = S_lds[o][lane + 192];
      float m = fmaxf(fmaxf(v0, v1), fmaxf(v2, v3));
      for (int off = 32; off; off >>= 1) m = fmaxf(m, __shfl_xor(m, off, 64));
      const float e0 = __expf(v0 - m), e1 = __expf(v1 - m);
      const float e2 = __expf(v2 - m), e3 = __expf(v3 - m);
      float s = e0 + e1 + e2 + e3;
      for (int off = 32; off; off >>= 1) s += __shfl_xor(s, off, 64);
      const float inv = 1.f / s;
      S_lds[o][lane] = e0 * inv; S_lds[o][lane + 64] = e1 * inv;
      S_lds[o][lane + 128] = e2 * inv; S_lds[o][lane + 192] = e3 * inv;
    }
  }
  __syncthreads();

  // ---- phase 4: out[o][d] = sum_r attn[o][r] * vproj[r][d] ----
  {
    const int d = tid & 63;
    const int tg = tid >> 6;
    const float* vp = &vproj[(size_t)bh * R_ * DP_ + d];
    float acc[8];
#pragma unroll
    for (int o = 0; o < 8; ++o) acc[o] = 0.f;
    for (int r = 0; r < R_; ++r) {
      const float vv = vp[r * DP_];
#pragma unroll
      for (int o = 0; o < 8; ++o) acc[o] += S_lds[tg * 8 + o][r] * vv;
    }
#pragma unroll
    for (int o = 0; o < 8; ++o) {
      const int s = s0 + tg * 8 + o;
      ao[((size_t)(b * S_ + s)) * D_ + h * DP_ + d] = acc[o];
    }
  }
}

// ============================================================
extern "C" void kernel_launch(void* const* d_in, const int* in_sizes, int n_in,
                              void* d_out, int out_size, void* d_ws, size_t ws_size,
                              hipStream_t stream) {
  const float* x = (const float*)d_in[0];
  const float* wq = (const float*)d_in[1];
  const float* wk = (const float*)d_in[2];
  const float* wv = (const float*)d_in[3];
  const float* E = (const float*)d_in[4];
  const float* F = (const float*)d_in[5];
  const float* ck = (const float*)d_in[6];
  const float* cb = (const float*)d_in[7];
  const float* wo = (const float*)d_in[8];
  const float* bo = (const float*)d_in[9];
  float* out = (float*)d_out;

  float* ws = (float*)d_ws;
  const size_t QN = (size_t)B_ * S_ * D_;       // 16,777,216
  const size_t PN = (size_t)B_ * H_ * R_ * DP_; // 4,194,304
  float* q = ws;
  float* k = q + QN;
  float* v = k + QN;
  float* kproj = v + QN;
  float* vproj = kproj + PN;
  float* ao = k;  // alias: k dead after proj_gemm

  {
    dim3 g(D_ / 128, (B_ * S_) / 128, 3);
    qkv_gemm_kernel<<<g, 256, 0, stream>>>(x, wq, wk, wv, q, k, v);
  }
  {
    dim3 g(R_ / 64, B_ * H_, 2);
    proj_gemm_kernel<<<g, 256, 0, stream>>>(k, v, E, F, kproj, vproj);
  }
  {
    dim3 g(S_ / TS_, B_ * H_, 1);
    attn_fused_kernel<<<g, 256, 0, stream>>>(q, kproj, vproj, ck, cb, ao);
  }
  {
    dim3 g(D_ / 128, (B_ * S_) / 128, 1);
    out_gemm_kernel<<<g, 256, 0, stream>>>(ao, wo, bo, out);
  }
}

// Round 2
// 1419.722 us; speedup vs baseline: 3.3952x; 3.3952x over previous
//
#include <hip/hip_runtime.h>

#define B_ 4
#define S_ 4096
#define D_ 1024
#define H_ 16
#define R_ 256
#define DP_ 64
#define TS_ 32

typedef short bf16x8 __attribute__((ext_vector_type(8)));
typedef short short4v __attribute__((ext_vector_type(4)));
typedef float f32x4 __attribute__((ext_vector_type(4)));

__device__ __forceinline__ short f2bf(float f) {
  unsigned u = __builtin_bit_cast(unsigned, f);
  u += 0x7fffu + ((u >> 16) & 1u);
  return (short)(u >> 16);
}
__device__ __forceinline__ float bf2f(short s) {
  unsigned u = ((unsigned)(unsigned short)s) << 16;
  return __builtin_bit_cast(float, u);
}

// ============================================================
// x fp32 -> bf16
// ============================================================
__global__ __launch_bounds__(256) void convert_x_kernel(const float* __restrict__ x,
                                                        short* __restrict__ xb) {
  const int n8 = (B_ * S_ * D_) / 8;
  int i = blockIdx.x * 256 + threadIdx.x;
  const int stride = gridDim.x * 256;
  for (; i < n8; i += stride) {
    const float4 a = ((const float4*)x)[2 * i];
    const float4 b = ((const float4*)x)[2 * i + 1];
    bf16x8 o;
    o[0] = f2bf(a.x); o[1] = f2bf(a.y); o[2] = f2bf(a.z); o[3] = f2bf(a.w);
    o[4] = f2bf(b.x); o[5] = f2bf(b.y); o[6] = f2bf(b.z); o[7] = f2bf(b.w);
    ((bf16x8*)xb)[i] = o;
  }
}

// ============================================================
// weight [K][N] fp32 -> wT [N][K] bf16  (z selects wq/wk/wv/wo)
// ============================================================
__global__ __launch_bounds__(256) void transpose_w_kernel(
    const float* __restrict__ w0, const float* __restrict__ w1,
    const float* __restrict__ w2, const float* __restrict__ w3,
    short* __restrict__ wT) {
  __shared__ float tile[64][65];
  const int z = blockIdx.z;
  const float* W = (z == 0) ? w0 : (z == 1) ? w1 : (z == 2) ? w2 : w3;
  short* out = wT + (size_t)z * (D_ * D_);
  const int k0 = blockIdx.y * 64;
  const int n0 = blockIdx.x * 64;
  const int tid = threadIdx.x;
#pragma unroll
  for (int q = 0; q < 4; ++q) {
    const int rr = (tid >> 4) + (q << 4);
    const float4 v = *(const float4*)&W[(size_t)(k0 + rr) * D_ + n0 + ((tid & 15) << 2)];
    tile[rr][(tid & 15) * 4 + 0] = v.x;
    tile[rr][(tid & 15) * 4 + 1] = v.y;
    tile[rr][(tid & 15) * 4 + 2] = v.z;
    tile[rr][(tid & 15) * 4 + 3] = v.w;
  }
  __syncthreads();
#pragma unroll
  for (int q = 0; q < 2; ++q) {
    const int nr = (tid >> 3) + (q << 5);
    const int c8 = (tid & 7) << 3;
    bf16x8 o;
#pragma unroll
    for (int j = 0; j < 8; ++j) o[j] = f2bf(tile[c8 + j][nr]);
    *(bf16x8*)&out[(size_t)(n0 + nr) * D_ + k0 + c8] = o;
  }
}

// ============================================================
// Toeplitz matrix: Tt[i][r][c] = ck[i*256 + (c-r+127)] (0 outside)
// ============================================================
__global__ __launch_bounds__(256) void build_T_kernel(const float* __restrict__ ck,
                                                      short* __restrict__ Tt) {
  const int idx = blockIdx.x * 256 + threadIdx.x;  // 3*256*256 total
  const int i = idx >> 16;
  const int r = (idx >> 8) & 255;
  const int c = idx & 255;
  const int j = c - r + 127;
  const float v = (j >= 0 && j < 256) ? ck[i * 256 + j] : 0.f;
  Tt[idx] = f2bf(v);
}

// ============================================================
// bf16 MFMA GEMM: C[M][1024] = A[M][1024] @ Bt[1024][1024]^T
// A row-major [M][K] bf16; Bt is [N][K] bf16 (pre-transposed).
// 128x128 tile, BK=32, 4 waves, 64x64 per wave (4x4 frags 16x16x32).
// ============================================================
template <bool OUT_BF16>
__device__ __forceinline__ void mfma_gemm_1024(const short* __restrict__ A,
                                               const short* __restrict__ Bt,
                                               void* __restrict__ Cout,
                                               const float* __restrict__ bias) {
  __shared__ short As[128 * 32];
  __shared__ short Bs[128 * 32];
  const int tid = threadIdx.x;
  const int w = tid >> 6, l = tid & 63;
  const int m0 = blockIdx.y * 128, n0 = blockIdx.x * 128;

  // staging: wave w covers LDS rows w*32 .. w*32+31 (two 16-row passes)
  const int srow = (w << 5) + (l >> 2);
  const int gchunk = l & 3;  // 16B chunk within 64B row
  // LDS[r][c] = G[r][c ^ (r&3)]  (chunk-level XOR swizzle)
  const int schunkX = ((gchunk ^ (srow & 3)) << 4);
  const short* Ag = A + (size_t)(m0 + srow) * D_ + (gchunk << 3);
  const short* Bg = Bt + (size_t)(n0 + srow) * D_ + (gchunk << 3);
  char* AsW = (char*)As + srow * 64 + schunkX;
  char* BsW = (char*)Bs + srow * 64 + schunkX;

  const int wr = ((w >> 1) << 6);
  const int wc = ((w & 1) << 6);
  const int fx = (l >> 4) ^ (l & 3);  // swizzled read chunk (row&3 == l&3 for frag rows)

  f32x4 acc[4][4];
#pragma unroll
  for (int i = 0; i < 4; ++i)
#pragma unroll
    for (int j = 0; j < 4; ++j) acc[i][j] = (f32x4){0.f, 0.f, 0.f, 0.f};

  for (int k0 = 0; k0 < D_; k0 += 32) {
    const bf16x8 a0 = *(const bf16x8*)(Ag + k0);
    const bf16x8 a1 = *(const bf16x8*)(Ag + (size_t)16 * D_ + k0);
    const bf16x8 b0 = *(const bf16x8*)(Bg + k0);
    const bf16x8 b1 = *(const bf16x8*)(Bg + (size_t)16 * D_ + k0);
    __syncthreads();
    *(bf16x8*)AsW = a0;
    *(bf16x8*)(AsW + 1024) = a1;
    *(bf16x8*)BsW = b0;
    *(bf16x8*)(BsW + 1024) = b1;
    __syncthreads();
    bf16x8 af[4], bfv[4];
#pragma unroll
    for (int t = 0; t < 4; ++t) {
      const int ar = wr + (t << 4) + (l & 15);
      af[t] = *(const bf16x8*)((char*)As + ar * 64 + (fx << 4));
      const int br = wc + (t << 4) + (l & 15);
      bfv[t] = *(const bf16x8*)((char*)Bs + br * 64 + (fx << 4));
    }
#pragma unroll
    for (int i = 0; i < 4; ++i)
#pragma unroll
      for (int j = 0; j < 4; ++j)
        acc[i][j] = __builtin_amdgcn_mfma_f32_16x16x32_bf16(af[i], bfv[j], acc[i][j], 0, 0, 0);
  }

#pragma unroll
  for (int i = 0; i < 4; ++i) {
#pragma unroll
    for (int r = 0; r < 4; ++r) {
      const int row = m0 + wr + (i << 4) + ((l >> 4) << 2) + r;
#pragma unroll
      for (int j = 0; j < 4; ++j) {
        const int col = n0 + wc + (j << 4) + (l & 15);
        const float vv = acc[i][j][r];
        if (OUT_BF16)
          ((short*)Cout)[(size_t)row * D_ + col] = f2bf(vv);
        else
          ((float*)Cout)[(size_t)row * D_ + col] = vv + bias[col];
      }
    }
  }
}

__global__ __launch_bounds__(256) void qkv_mfma_kernel(
    const short* __restrict__ xb, const short* __restrict__ wT,
    short* __restrict__ qb, short* __restrict__ kb, short* __restrict__ vb) {
  const int z = blockIdx.z;
  const short* Bt = wT + (size_t)z * (D_ * D_);
  short* C = (z == 0) ? qb : (z == 1) ? kb : vb;
  mfma_gemm_1024<true>(xb, Bt, C, nullptr);
}

__global__ __launch_bounds__(256) void out_mfma_kernel(
    const short* __restrict__ aob, const short* __restrict__ woT,
    const float* __restrict__ bo, float* __restrict__ out) {
  mfma_gemm_1024<false>(aob, woT, out, bo);
}

// ============================================================
// kproj/vproj (fp32 accumulate; k/v inputs bf16, E/F fp32)
// out[r][d] = sum_n P[h][n][r] * src[b][n][h*64+d]
// grid: (R/64=4, B*H=64, 2)
// ============================================================
__global__ __launch_bounds__(256) void proj_gemm_kernel(
    const short* __restrict__ kbuf, const short* __restrict__ vbuf,
    const float* __restrict__ E, const float* __restrict__ F,
    float* __restrict__ kproj, float* __restrict__ vproj) {
  __shared__ float Es[16][64];
  __shared__ float Ks[16][64];
  const int tid = threadIdx.x;
  const int tx = tid & 15;
  const int ty = tid >> 4;
  const int bh = blockIdx.y;
  const int b = bh >> 4, h = bh & 15;
  const int r0 = blockIdx.x * 64;

  const short* src = blockIdx.z ? vbuf : kbuf;
  const float* P = blockIdx.z ? F : E;
  float* outp = blockIdx.z ? vproj : kproj;

  const float* Pbase = P + (size_t)h * S_ * R_;
  const short* src_b = src + (size_t)b * S_ * D_ + h * DP_;

  const int nl = tid >> 4;
  const int cl = (tid & 15) << 2;

  float acc[4][4];
#pragma unroll
  for (int i = 0; i < 4; ++i)
#pragma unroll
    for (int j = 0; j < 4; ++j) acc[i][j] = 0.f;

  for (int n0 = 0; n0 < S_; n0 += 16) {
    const float4 e = *(const float4*)&Pbase[(size_t)(n0 + nl) * R_ + r0 + cl];
    const short4v kv = *(const short4v*)&src_b[(size_t)(n0 + nl) * D_ + cl];
    __syncthreads();
    *(float4*)&Es[nl][cl] = e;
    Ks[nl][cl + 0] = bf2f(kv[0]);
    Ks[nl][cl + 1] = bf2f(kv[1]);
    Ks[nl][cl + 2] = bf2f(kv[2]);
    Ks[nl][cl + 3] = bf2f(kv[3]);
    __syncthreads();
#pragma unroll
    for (int kk = 0; kk < 16; ++kk) {
      float a[4], bb[4];
      *(float4*)&a[0] = *(const float4*)&Es[kk][ty << 2];
      *(float4*)&bb[0] = *(const float4*)&Ks[kk][tx << 2];
#pragma unroll
      for (int i = 0; i < 4; ++i)
#pragma unroll
        for (int j = 0; j < 4; ++j) acc[i][j] += a[i] * bb[j];
    }
  }

#pragma unroll
  for (int i = 0; i < 4; ++i) {
    const int r = r0 + (ty << 2) + i;
    float4 v;
    v.x = acc[i][0]; v.y = acc[i][1]; v.z = acc[i][2]; v.w = acc[i][3];
    *(float4*)&outp[((size_t)bh * R_ + r) * DP_ + (tx << 2)] = v;
  }
}

// ============================================================
// Fused: scores(fp32->bf16 LDS) -> conv via Toeplitz MFMA ->
//        softmax(fp32) -> attn@vproj -> ao (bf16)
// grid: (S/32=128, B*H=64), 256 threads (4 waves)
// ============================================================
__global__ __launch_bounds__(256) void attn_fused_kernel(
    const short* __restrict__ qb, const float* __restrict__ kproj,
    const float* __restrict__ vproj, const short* __restrict__ Tt,
    const float* __restrict__ cbias, short* __restrict__ aob) {
  __shared__ char smem[50176];
  // Sb: [34][256] bf16 swizzled, bytes 0..17407
  float* qld = (float*)(smem + 17408);  // [34][64] fp32 (dead after phase 1)
  float* Sf = (float*)(smem + 17408);   // [32][256] fp32 (phases 2b-4)

  const int tid = threadIdx.x;
  const int w = tid >> 6, l = tid & 63;
  const int s0 = blockIdx.x * TS_;
  const int bh = blockIdx.y;
  const int b = bh >> 4, h = bh & 15;

  // load q rows (with halo) -> fp32 LDS
  for (int idx = tid; idx < 34 * 16; idx += 256) {
    const int t = idx >> 4, c4 = (idx & 15) << 2;
    const int s = s0 - 1 + t;
    float4 v = {0.f, 0.f, 0.f, 0.f};
    if (s >= 0 && s < S_) {
      const short4v sv = *(const short4v*)&qb[((size_t)(b * S_ + s)) * D_ + h * DP_ + c4];
      v.x = bf2f(sv[0]); v.y = bf2f(sv[1]); v.z = bf2f(sv[2]); v.w = bf2f(sv[3]);
    }
    *(float4*)&qld[t * 64 + c4] = v;
  }
  __syncthreads();

  // ---- phase 1: scores -> Sb bf16 (swizzled) ----
  {
    const int r = tid;
    float kp[64];
    const float* kpr = &kproj[((size_t)bh * R_ + r) * DP_];
#pragma unroll
    for (int d4 = 0; d4 < 64; d4 += 4) *(float4*)&kp[d4] = *(const float4*)&kpr[d4];
    for (int t = 0; t < 34; ++t) {
      float p0 = 0.f, p1 = 0.f, p2 = 0.f, p3 = 0.f;
#pragma unroll
      for (int d = 0; d < 64; d += 4) {
        p0 += qld[t * 64 + d + 0] * kp[d + 0];
        p1 += qld[t * 64 + d + 1] * kp[d + 1];
        p2 += qld[t * 64 + d + 2] * kp[d + 2];
        p3 += qld[t * 64 + d + 3] * kp[d + 3];
      }
      const int off = t * 512 + ((2 * r) ^ ((t & 7) << 4));
      *(short*)(smem + off) = f2bf((p0 + p1 + p2 + p3) * 0.125f);
    }
  }
  __syncthreads();

  // ---- phase 2: conv = sum_i Sb[o+i][:] @ Tt[i][:][:]^T via MFMA ----
  f32x4 cacc[2][4];
#pragma unroll
  for (int rt = 0; rt < 2; ++rt)
#pragma unroll
    for (int j = 0; j < 4; ++j) cacc[rt][j] = (f32x4){0.f, 0.f, 0.f, 0.f};

#pragma unroll
  for (int i = 0; i < 3; ++i) {
    const short* Ti = Tt + (size_t)i * 65536;
#pragma unroll
    for (int c8 = 0; c8 < 8; ++c8) {
      const int kb = c8 * 64 + ((l >> 4) << 4);  // byte offset of 16B chunk in Sb row
      const int r0 = (l & 15) + i;
      const int r1 = r0 + 16;
      const bf16x8 a0 = *(const bf16x8*)(smem + r0 * 512 + (kb ^ ((r0 & 7) << 4)));
      const bf16x8 a1 = *(const bf16x8*)(smem + r1 * 512 + (kb ^ ((r1 & 7) << 4)));
      const int kk = c8 * 32 + ((l >> 4) << 3);  // element offset in Tt row
#pragma unroll
      for (int j = 0; j < 4; ++j) {
        const bf16x8 bv = *(const bf16x8*)(Ti + (size_t)(w * 64 + j * 16 + (l & 15)) * 256 + kk);
        cacc[0][j] = __builtin_amdgcn_mfma_f32_16x16x32_bf16(a0, bv, cacc[0][j], 0, 0, 0);
        cacc[1][j] = __builtin_amdgcn_mfma_f32_16x16x32_bf16(a1, bv, cacc[1][j], 0, 0, 0);
      }
    }
  }
  // write conv result (+bias) to Sf
  {
    const float cb0 = cbias[0];
#pragma unroll
    for (int rt = 0; rt < 2; ++rt)
#pragma unroll
      for (int j = 0; j < 4; ++j)
#pragma unroll
        for (int r = 0; r < 4; ++r) {
          const int row = rt * 16 + ((l >> 4) << 2) + r;
          const int col = w * 64 + j * 16 + (l & 15);
          Sf[row * 256 + col] = cacc[rt][j][r] + cb0;
        }
  }
  __syncthreads();

  // ---- phase 3: softmax over r ----
  {
    for (int ii = 0; ii < 8; ++ii) {
      const int o = w * 8 + ii;
      float v0 = Sf[o * 256 + l], v1 = Sf[o * 256 + l + 64];
      float v2 = Sf[o * 256 + l + 128], v3 = Sf[o * 256 + l + 192];
      float m = fmaxf(fmaxf(v0, v1), fmaxf(v2, v3));
      for (int off = 32; off; off >>= 1) m = fmaxf(m, __shfl_xor(m, off, 64));
      const float e0 = __expf(v0 - m), e1 = __expf(v1 - m);
      const float e2 = __expf(v2 - m), e3 = __expf(v3 - m);
      float s = e0 + e1 + e2 + e3;
      for (int off = 32; off; off >>= 1) s += __shfl_xor(s, off, 64);
      const float inv = 1.f / s;
      Sf[o * 256 + l] = e0 * inv;
      Sf[o * 256 + l + 64] = e1 * inv;
      Sf[o * 256 + l + 128] = e2 * inv;
      Sf[o * 256 + l + 192] = e3 * inv;
    }
  }
  __syncthreads();

  // ---- phase 4: out[o][d] = sum_r attn[o][r] * vproj[r][d] -> bf16 ----
  {
    const int d = l;
    const float* vp = &vproj[(size_t)bh * R_ * DP_ + d];
    float acc[8];
#pragma unroll
    for (int o = 0; o < 8; ++o) acc[o] = 0.f;
    for (int r = 0; r < R_; ++r) {
      const float vv = vp[r * DP_];
#pragma unroll
      for (int o = 0; o < 8; ++o) acc[o] += Sf[(w * 8 + o) * 256 + r] * vv;
    }
#pragma unroll
    for (int o = 0; o < 8; ++o) {
      const int s = s0 + w * 8 + o;
      aob[((size_t)(b * S_ + s)) * D_ + h * DP_ + d] = f2bf(acc[o]);
    }
  }
}

// ============================================================
extern "C" void kernel_launch(void* const* d_in, const int* in_sizes, int n_in,
                              void* d_out, int out_size, void* d_ws, size_t ws_size,
                              hipStream_t stream) {
  const float* x = (const float*)d_in[0];
  const float* wq = (const float*)d_in[1];
  const float* wk = (const float*)d_in[2];
  const float* wv = (const float*)d_in[3];
  const float* E = (const float*)d_in[4];
  const float* F = (const float*)d_in[5];
  const float* ck = (const float*)d_in[6];
  const float* cb = (const float*)d_in[7];
  const float* wo = (const float*)d_in[8];
  const float* bo = (const float*)d_in[9];
  float* out = (float*)d_out;

  const size_t QN = (size_t)B_ * S_ * D_;  // 16,777,216
  const size_t WN = (size_t)D_ * D_;       // 1,048,576
  const size_t PN = (size_t)B_ * H_ * R_ * DP_;  // 4,194,304

  short* xb = (short*)d_ws;
  short* wT = xb + QN;          // 4 weights [N][K] bf16
  short* qb = wT + 4 * WN;
  short* kb = qb + QN;
  short* vb = kb + QN;
  float* kproj = (float*)(vb + QN);
  float* vproj = kproj + PN;
  short* Tt = xb;   // alias xb (built AFTER qkv consumes xb)
  short* aob = kb;  // alias kb (written AFTER proj consumes kb)

  convert_x_kernel<<<2048, 256, 0, stream>>>(x, xb);
  {
    dim3 g(16, 16, 4);
    transpose_w_kernel<<<g, 256, 0, stream>>>(wq, wk, wv, wo, wT);
  }
  {
    dim3 g(D_ / 128, (B_ * S_) / 128, 3);
    qkv_mfma_kernel<<<g, 256, 0, stream>>>(xb, wT, qb, kb, vb);
  }
  build_T_kernel<<<768, 256, 0, stream>>>(ck, Tt);
  {
    dim3 g(R_ / 64, B_ * H_, 2);
    proj_gemm_kernel<<<g, 256, 0, stream>>>(kb, vb, E, F, kproj, vproj);
  }
  {
    dim3 g(S_ / TS_, B_ * H_, 1);
    attn_fused_kernel<<<g, 256, 0, stream>>>(qb, kproj, vproj, Tt, cb, aob);
  }
  {
    dim3 g(D_ / 128, (B_ * S_) / 128, 1);
    out_mfma_kernel<<<g, 256, 0, stream>>>(aob, wT + 3 * WN, bo, out);
  }
}

// Round 3
// 991.331 us; speedup vs baseline: 4.8624x; 1.4321x over previous
//
#include <hip/hip_runtime.h>

#define B_ 4
#define S_ 4096
#define D_ 1024
#define H_ 16
#define R_ 256
#define DP_ 64

typedef short bf16x8 __attribute__((ext_vector_type(8)));
typedef short short4v __attribute__((ext_vector_type(4)));
typedef float f32x4 __attribute__((ext_vector_type(4)));

__device__ __forceinline__ short f2bf(float f) {
  unsigned u = __builtin_bit_cast(unsigned, f);
  u += 0x7fffu + ((u >> 16) & 1u);
  return (short)(u >> 16);
}
__device__ __forceinline__ float bf2f(short s) {
  unsigned u = ((unsigned)(unsigned short)s) << 16;
  return __builtin_bit_cast(float, u);
}

// ============================================================
// x fp32 -> bf16
// ============================================================
__global__ __launch_bounds__(256) void convert_x_kernel(const float* __restrict__ x,
                                                        short* __restrict__ xb) {
  const int n8 = (B_ * S_ * D_) / 8;
  int i = blockIdx.x * 256 + threadIdx.x;
  const int stride = gridDim.x * 256;
  for (; i < n8; i += stride) {
    const float4 a = ((const float4*)x)[2 * i];
    const float4 b = ((const float4*)x)[2 * i + 1];
    bf16x8 o;
    o[0] = f2bf(a.x); o[1] = f2bf(a.y); o[2] = f2bf(a.z); o[3] = f2bf(a.w);
    o[4] = f2bf(b.x); o[5] = f2bf(b.y); o[6] = f2bf(b.z); o[7] = f2bf(b.w);
    ((bf16x8*)xb)[i] = o;
  }
}

// ============================================================
// weight [K][N] fp32 -> wT [N][K] bf16  (z selects wq/wk/wv/wo)
// ============================================================
__global__ __launch_bounds__(256) void transpose_w_kernel(
    const float* __restrict__ w0, const float* __restrict__ w1,
    const float* __restrict__ w2, const float* __restrict__ w3,
    short* __restrict__ wT) {
  __shared__ float tile[64][65];
  const int z = blockIdx.z;
  const float* W = (z == 0) ? w0 : (z == 1) ? w1 : (z == 2) ? w2 : w3;
  short* out = wT + (size_t)z * (D_ * D_);
  const int k0 = blockIdx.y * 64;
  const int n0 = blockIdx.x * 64;
  const int tid = threadIdx.x;
#pragma unroll
  for (int q = 0; q < 4; ++q) {
    const int rr = (tid >> 4) + (q << 4);
    const float4 v = *(const float4*)&W[(size_t)(k0 + rr) * D_ + n0 + ((tid & 15) << 2)];
    tile[rr][(tid & 15) * 4 + 0] = v.x;
    tile[rr][(tid & 15) * 4 + 1] = v.y;
    tile[rr][(tid & 15) * 4 + 2] = v.z;
    tile[rr][(tid & 15) * 4 + 3] = v.w;
  }
  __syncthreads();
#pragma unroll
  for (int q = 0; q < 2; ++q) {
    const int nr = (tid >> 3) + (q << 5);
    const int c8 = (tid & 7) << 3;
    bf16x8 o;
#pragma unroll
    for (int j = 0; j < 8; ++j) o[j] = f2bf(tile[c8 + j][nr]);
    *(bf16x8*)&out[(size_t)(n0 + nr) * D_ + k0 + c8] = o;
  }
}

// ============================================================
// Toeplitz: Tt[i][r][c] = ck[i*256 + (c-r+127)] * 0.125 (0 outside)
// (scale folded in; conv bias dropped — cancels in softmax)
// ============================================================
__global__ __launch_bounds__(256) void build_T_kernel(const float* __restrict__ ck,
                                                      short* __restrict__ Tt) {
  const int idx = blockIdx.x * 256 + threadIdx.x;  // 3*256*256 total
  const int i = idx >> 16;
  const int r = (idx >> 8) & 255;
  const int c = idx & 255;
  const int j = c - r + 127;
  const float v = (j >= 0 && j < 256) ? ck[i * 256 + j] * 0.125f : 0.f;
  Tt[idx] = f2bf(v);
}

// ============================================================
// bf16 MFMA GEMM: C[M][1024] = A[M][1024] @ Bt[1024][1024]^T
// ============================================================
template <bool OUT_BF16>
__device__ __forceinline__ void mfma_gemm_1024(const short* __restrict__ A,
                                               const short* __restrict__ Bt,
                                               void* __restrict__ Cout,
                                               const float* __restrict__ bias) {
  __shared__ short As[128 * 32];
  __shared__ short Bs[128 * 32];
  const int tid = threadIdx.x;
  const int w = tid >> 6, l = tid & 63;
  const int m0 = blockIdx.y * 128, n0 = blockIdx.x * 128;

  const int srow = (w << 5) + (l >> 2);
  const int gchunk = l & 3;
  const int schunkX = ((gchunk ^ (srow & 3)) << 4);
  const short* Ag = A + (size_t)(m0 + srow) * D_ + (gchunk << 3);
  const short* Bg = Bt + (size_t)(n0 + srow) * D_ + (gchunk << 3);
  char* AsW = (char*)As + srow * 64 + schunkX;
  char* BsW = (char*)Bs + srow * 64 + schunkX;

  const int wr = ((w >> 1) << 6);
  const int wc = ((w & 1) << 6);
  const int fx = (l >> 4) ^ (l & 3);

  f32x4 acc[4][4];
#pragma unroll
  for (int i = 0; i < 4; ++i)
#pragma unroll
    for (int j = 0; j < 4; ++j) acc[i][j] = (f32x4){0.f, 0.f, 0.f, 0.f};

  for (int k0 = 0; k0 < D_; k0 += 32) {
    const bf16x8 a0 = *(const bf16x8*)(Ag + k0);
    const bf16x8 a1 = *(const bf16x8*)(Ag + (size_t)16 * D_ + k0);
    const bf16x8 b0 = *(const bf16x8*)(Bg + k0);
    const bf16x8 b1 = *(const bf16x8*)(Bg + (size_t)16 * D_ + k0);
    __syncthreads();
    *(bf16x8*)AsW = a0;
    *(bf16x8*)(AsW + 1024) = a1;
    *(bf16x8*)BsW = b0;
    *(bf16x8*)(BsW + 1024) = b1;
    __syncthreads();
    bf16x8 af[4], bfv[4];
#pragma unroll
    for (int t = 0; t < 4; ++t) {
      const int ar = wr + (t << 4) + (l & 15);
      af[t] = *(const bf16x8*)((char*)As + ar * 64 + (fx << 4));
      const int br = wc + (t << 4) + (l & 15);
      bfv[t] = *(const bf16x8*)((char*)Bs + br * 64 + (fx << 4));
    }
#pragma unroll
    for (int i = 0; i < 4; ++i)
#pragma unroll
      for (int j = 0; j < 4; ++j)
        acc[i][j] = __builtin_amdgcn_mfma_f32_16x16x32_bf16(af[i], bfv[j], acc[i][j], 0, 0, 0);
  }

#pragma unroll
  for (int i = 0; i < 4; ++i) {
#pragma unroll
    for (int r = 0; r < 4; ++r) {
      const int row = m0 + wr + (i << 4) + ((l >> 4) << 2) + r;
#pragma unroll
      for (int j = 0; j < 4; ++j) {
        const int col = n0 + wc + (j << 4) + (l & 15);
        const float vv = acc[i][j][r];
        if (OUT_BF16)
          ((short*)Cout)[(size_t)row * D_ + col] = f2bf(vv);
        else
          ((float*)Cout)[(size_t)row * D_ + col] = vv + bias[col];
      }
    }
  }
}

__global__ __launch_bounds__(256) void qkv_mfma_kernel(
    const short* __restrict__ xb, const short* __restrict__ wT,
    short* __restrict__ qb, short* __restrict__ kb, short* __restrict__ vb) {
  const int z = blockIdx.z;
  const short* Bt = wT + (size_t)z * (D_ * D_);
  short* C = (z == 0) ? qb : (z == 1) ? kb : vb;
  mfma_gemm_1024<true>(xb, Bt, C, nullptr);
}

__global__ __launch_bounds__(256) void out_mfma_kernel(
    const short* __restrict__ aob, const short* __restrict__ woT,
    const float* __restrict__ bo, float* __restrict__ out) {
  mfma_gemm_1024<false>(aob, woT, out, bo);
}

// ============================================================
// k/v [b][n][h*64+d] bf16 -> kT/vT [bh][d][n] bf16 (64n x 64d tiles)
// ============================================================
__global__ __launch_bounds__(256) void transpose_kv_kernel(
    const short* __restrict__ kb, const short* __restrict__ vb,
    short* __restrict__ kTb, short* __restrict__ vTb) {
  __shared__ short tile[64 * 80];
  const int tid = threadIdx.x;
  const int n0 = blockIdx.x * 64;
  const int bh = blockIdx.y;
  const int b = bh >> 4, h = bh & 15;
  const short* src = blockIdx.z ? vb : kb;
  short* dst = blockIdx.z ? vTb : kTb;
#pragma unroll
  for (int q = 0; q < 2; ++q) {
    const int idx = tid + q * 256;
    const int n = idx >> 3, c = idx & 7;
    *(bf16x8*)&tile[n * 80 + c * 8] =
        *(const bf16x8*)&src[((size_t)b * S_ + n0 + n) * D_ + h * DP_ + c * 8];
  }
  __syncthreads();
#pragma unroll
  for (int q = 0; q < 2; ++q) {
    const int idx = tid + q * 256;
    const int d = idx >> 3, cc = idx & 7;
    bf16x8 o;
#pragma unroll
    for (int j = 0; j < 8; ++j) o[j] = tile[(cc * 8 + j) * 80 + d];
    *(bf16x8*)&dst[((size_t)bh * DP_ + d) * S_ + n0 + cc * 8] = o;
  }
}

// ============================================================
// E/F fp32 [h][n][r] -> ET/FT bf16 [h][r][n] (64n x 64r tiles)
// ============================================================
__global__ __launch_bounds__(256) void transpose_EF_kernel(
    const float* __restrict__ E, const float* __restrict__ F,
    short* __restrict__ ETb, short* __restrict__ FTb) {
  __shared__ float tile[64][65];
  const int tid = threadIdx.x;
  const int n0 = blockIdx.x * 64;
  const int r0 = blockIdx.y * 64;
  const int hz = blockIdx.z;
  const int h = hz & 15;
  const float* src = (hz < 16) ? E : F;
  short* dst = (hz < 16) ? ETb : FTb;
  const float* base = src + ((size_t)h * S_ + n0) * R_ + r0;
#pragma unroll
  for (int q = 0; q < 4; ++q) {
    const int n = (tid >> 4) + q * 16;
    const int r4 = (tid & 15) << 2;
    const float4 v = *(const float4*)&base[(size_t)n * R_ + r4];
    tile[n][r4 + 0] = v.x; tile[n][r4 + 1] = v.y;
    tile[n][r4 + 2] = v.z; tile[n][r4 + 3] = v.w;
  }
  __syncthreads();
#pragma unroll
  for (int q = 0; q < 2; ++q) {
    const int r = (tid >> 3) + q * 32;
    const int n8 = (tid & 7) << 3;
    bf16x8 o;
#pragma unroll
    for (int j = 0; j < 8; ++j) o[j] = f2bf(tile[n8 + j][r]);
    *(bf16x8*)&dst[((size_t)h * R_ + r0 + r) * S_ + n0 + n8] = o;
  }
}

// ============================================================
// proj MFMA: per (bh): C[128r x 64d] = ET[128r][4096n] @ kT[64d][4096n]^T
// grid (2 rhalf, 64 bh, 2 z). z=0 -> kprojb [bh][r][d]; z=1 -> vprojT [bh][d][r]
// ============================================================
__global__ __launch_bounds__(256) void proj_mfma_kernel(
    const short* __restrict__ ETb, const short* __restrict__ FTb,
    const short* __restrict__ kTb, const short* __restrict__ vTb,
    short* __restrict__ kprojb, short* __restrict__ vprojTb) {
  __shared__ short As[128 * 64];
  __shared__ short Bs[64 * 64];
  const int tid = threadIdx.x;
  const int w = tid >> 6, l = tid & 63;
  const int l15 = l & 15, l16 = l >> 4;
  const int r0 = blockIdx.x * 128;
  const int bh = blockIdx.y;
  const int h = bh & 15;
  const int z = blockIdx.z;
  const short* Ab = (z ? FTb : ETb) + ((size_t)h * R_ + r0) * S_;
  const short* Bb = (z ? vTb : kTb) + (size_t)bh * DP_ * S_;
  const int wm = w >> 1, wn = w & 1;

  f32x4 acc[4][2];
#pragma unroll
  for (int mt = 0; mt < 4; ++mt)
#pragma unroll
    for (int nt = 0; nt < 2; ++nt) acc[mt][nt] = (f32x4){0.f, 0.f, 0.f, 0.f};

  for (int k0 = 0; k0 < S_; k0 += 64) {
    bf16x8 a[4], bq[2];
#pragma unroll
    for (int j = 0; j < 4; ++j) {
      const int idx = tid + j * 256;
      const int ar = idx >> 3, c = idx & 7;
      a[j] = *(const bf16x8*)&Ab[(size_t)ar * S_ + k0 + c * 8];
    }
#pragma unroll
    for (int j = 0; j < 2; ++j) {
      const int idx = tid + j * 256;
      const int br = idx >> 3, c = idx & 7;
      bq[j] = *(const bf16x8*)&Bb[(size_t)br * S_ + k0 + c * 8];
    }
    __syncthreads();
#pragma unroll
    for (int j = 0; j < 4; ++j) {
      const int idx = tid + j * 256;
      const int ar = idx >> 3, c = idx & 7;
      *(bf16x8*)((char*)As + ar * 128 + ((c ^ (ar & 7)) << 4)) = a[j];
    }
#pragma unroll
    for (int j = 0; j < 2; ++j) {
      const int idx = tid + j * 256;
      const int br = idx >> 3, c = idx & 7;
      *(bf16x8*)((char*)Bs + br * 128 + ((c ^ (br & 7)) << 4)) = bq[j];
    }
    __syncthreads();
#pragma unroll
    for (int kk = 0; kk < 2; ++kk) {
      bf16x8 af[4], bfr[2];
#pragma unroll
      for (int mt = 0; mt < 4; ++mt) {
        const int row = wm * 64 + mt * 16 + l15;
        af[mt] = *(const bf16x8*)((char*)As + row * 128 + (((kk * 4 + l16) ^ (row & 7)) << 4));
      }
#pragma unroll
      for (int nt = 0; nt < 2; ++nt) {
        const int row = wn * 32 + nt * 16 + l15;
        bfr[nt] = *(const bf16x8*)((char*)Bs + row * 128 + (((kk * 4 + l16) ^ (row & 7)) << 4));
      }
#pragma unroll
      for (int mt = 0; mt < 4; ++mt)
#pragma unroll
        for (int nt = 0; nt < 2; ++nt)
          acc[mt][nt] = __builtin_amdgcn_mfma_f32_16x16x32_bf16(af[mt], bfr[nt], acc[mt][nt], 0, 0, 0);
    }
  }

  if (z == 0) {
#pragma unroll
    for (int mt = 0; mt < 4; ++mt)
#pragma unroll
      for (int nt = 0; nt < 2; ++nt)
#pragma unroll
        for (int rr = 0; rr < 4; ++rr) {
          const int r = r0 + wm * 64 + mt * 16 + l16 * 4 + rr;
          const int d = wn * 32 + nt * 16 + l15;
          kprojb[((size_t)bh * R_ + r) * DP_ + d] = f2bf(acc[mt][nt][rr]);
        }
  } else {
#pragma unroll
    for (int mt = 0; mt < 4; ++mt)
#pragma unroll
      for (int nt = 0; nt < 2; ++nt) {
        const int d = wn * 32 + nt * 16 + l15;
        const int rbase = r0 + wm * 64 + mt * 16 + l16 * 4;
        short4v o;
#pragma unroll
        for (int rr = 0; rr < 4; ++rr) o[rr] = f2bf(acc[mt][nt][rr]);
        *(short4v*)&vprojTb[((size_t)bh * DP_ + d) * R_ + rbase] = o;
      }
  }
}

// ============================================================
// Fused attn: scores(MFMA) -> conv(Toeplitz MFMA) -> softmax -> PV(MFMA)
// grid (S/64=64, BH=64), 256 threads (4 waves). TS=64 rows per block.
// LDS: Sb [80][256] bf16 swizzled (40960B) + q [80][64] bf16 (10240B)
// ============================================================
__global__ __launch_bounds__(256) void attn_fused_kernel(
    const short* __restrict__ qb, const short* __restrict__ kprojb,
    const short* __restrict__ vprojTb, const short* __restrict__ Tt,
    short* __restrict__ aob) {
  __shared__ char smem[51200];
  const int tid = threadIdx.x;
  const int w = tid >> 6, l = tid & 63;
  const int l15 = l & 15, l16 = l >> 4;
  const int s0 = blockIdx.x * 64;
  const int bh = blockIdx.y;
  const int b = bh >> 4, h = bh & 15;

  // phase 0: stage q rows s0-1 .. s0+78 (rows >= valid range zero-filled)
  for (int idx = tid; idx < 640; idx += 256) {
    const int t = idx >> 3, c = idx & 7;
    const int s = s0 - 1 + t;
    bf16x8 val = {0, 0, 0, 0, 0, 0, 0, 0};
    if (s >= 0 && s < S_)
      val = *(const bf16x8*)&qb[((size_t)(b * S_ + s)) * D_ + h * DP_ + c * 8];
    *(bf16x8*)(smem + 40960 + t * 128 + ((c ^ (t & 7)) << 4)) = val;
  }
  __syncthreads();

  // ---- phase 1: scores[t][r] = q[t][:] . kprojb[r][:]  (raw, scale in Tt) ----
  {
    bf16x8 av[5][2];
#pragma unroll
    for (int m = 0; m < 5; ++m)
#pragma unroll
      for (int kk = 0; kk < 2; ++kk) {
        const int row = m * 16 + l15;
        av[m][kk] = *(const bf16x8*)(smem + 40960 + row * 128 +
                                     (((kk * 4 + l16) ^ (row & 7)) << 4));
      }
#pragma unroll
    for (int n = 0; n < 4; ++n) {
      const int rcol = w * 64 + n * 16 + l15;
      const short* kpb = kprojb + ((size_t)bh * R_ + rcol) * DP_ + l16 * 8;
      const bf16x8 bv0 = *(const bf16x8*)kpb;
      const bf16x8 bv1 = *(const bf16x8*)(kpb + 32);
      f32x4 sa[5];
#pragma unroll
      for (int m = 0; m < 5; ++m) sa[m] = (f32x4){0.f, 0.f, 0.f, 0.f};
#pragma unroll
      for (int m = 0; m < 5; ++m) {
        sa[m] = __builtin_amdgcn_mfma_f32_16x16x32_bf16(av[m][0], bv0, sa[m], 0, 0, 0);
        sa[m] = __builtin_amdgcn_mfma_f32_16x16x32_bf16(av[m][1], bv1, sa[m], 0, 0, 0);
      }
#pragma unroll
      for (int m = 0; m < 5; ++m)
#pragma unroll
        for (int rr = 0; rr < 4; ++rr) {
          const int t = m * 16 + l16 * 4 + rr;
          const int off = t * 512 + (((rcol >> 3) ^ (t & 7)) << 4) + ((rcol & 7) << 1);
          *(short*)(smem + off) = f2bf(sa[m][rr]);
        }
    }
  }
  __syncthreads();

  // ---- phase 2: conv out[t][r] = sum_i Sb[t+i][:] . Tt[i][r][:] ----
  f32x4 cacc[4][4];
#pragma unroll
  for (int m = 0; m < 4; ++m)
#pragma unroll
    for (int n = 0; n < 4; ++n) cacc[m][n] = (f32x4){0.f, 0.f, 0.f, 0.f};

  for (int i = 0; i < 3; ++i) {
    const short* Ti = Tt + (size_t)i * 65536;
#pragma unroll
    for (int c8 = 0; c8 < 8; ++c8) {
      bf16x8 ca[4];
      const int ck = c8 * 4 + l16;
#pragma unroll
      for (int m = 0; m < 4; ++m) {
        const int row = m * 16 + l15 + i;
        ca[m] = *(const bf16x8*)(smem + row * 512 + ((ck ^ (row & 7)) << 4));
      }
#pragma unroll
      for (int n = 0; n < 4; ++n) {
        const bf16x8 bv = *(const bf16x8*)(Ti + ((size_t)(w * 64 + n * 16 + l15) << 8) +
                                           (c8 << 5) + (l16 << 3));
#pragma unroll
        for (int m = 0; m < 4; ++m)
          cacc[m][n] = __builtin_amdgcn_mfma_f32_16x16x32_bf16(ca[m], bv, cacc[m][n], 0, 0, 0);
      }
    }
  }
  __syncthreads();
#pragma unroll
  for (int m = 0; m < 4; ++m)
#pragma unroll
    for (int n = 0; n < 4; ++n)
#pragma unroll
      for (int rr = 0; rr < 4; ++rr) {
        const int t = m * 16 + l16 * 4 + rr;
        const int c = w * 64 + n * 16 + l15;
        const int off = t * 512 + (((c >> 3) ^ (t & 7)) << 4) + ((c & 7) << 1);
        *(short*)(smem + off) = f2bf(cacc[m][n][rr]);
      }
  __syncthreads();

  // ---- phase 3: softmax over r (rows w*16..w*16+15, full wave per row) ----
  for (int o = 0; o < 16; ++o) {
    const int t = w * 16 + o;
    const int off = t * 512 + ((((l >> 1) ^ (t & 7)) << 4)) + ((l & 1) << 3);
    short4v pv = *(short4v*)(smem + off);
    const float f0 = bf2f(pv[0]), f1 = bf2f(pv[1]), f2 = bf2f(pv[2]), f3 = bf2f(pv[3]);
    float mx = fmaxf(fmaxf(f0, f1), fmaxf(f2, f3));
    for (int d = 32; d; d >>= 1) mx = fmaxf(mx, __shfl_xor(mx, d, 64));
    const float e0 = __expf(f0 - mx), e1 = __expf(f1 - mx);
    const float e2 = __expf(f2 - mx), e3 = __expf(f3 - mx);
    float sm = e0 + e1 + e2 + e3;
    for (int d = 32; d; d >>= 1) sm += __shfl_xor(sm, d, 64);
    const float inv = 1.f / sm;
    short4v ov;
    ov[0] = f2bf(e0 * inv); ov[1] = f2bf(e1 * inv);
    ov[2] = f2bf(e2 * inv); ov[3] = f2bf(e3 * inv);
    *(short4v*)(smem + off) = ov;
  }
  __syncthreads();

  // ---- phase 4: PV. out[64][64] = P[64][256] @ vprojT[64][256]^T ----
  f32x4 pacc[4];
#pragma unroll
  for (int n = 0; n < 4; ++n) pacc[n] = (f32x4){0.f, 0.f, 0.f, 0.f};
#pragma unroll
  for (int kk = 0; kk < 8; ++kk) {
    const int row = w * 16 + l15;
    const int ck = kk * 4 + l16;
    const bf16x8 pa = *(const bf16x8*)(smem + row * 512 + ((ck ^ (row & 7)) << 4));
#pragma unroll
    for (int n = 0; n < 4; ++n) {
      const bf16x8 bv = *(const bf16x8*)(vprojTb + ((size_t)bh * DP_ + n * 16 + l15) * R_ +
                                         (kk << 5) + (l16 << 3));
      pacc[n] = __builtin_amdgcn_mfma_f32_16x16x32_bf16(pa, bv, pacc[n], 0, 0, 0);
    }
  }
#pragma unroll
  for (int n = 0; n < 4; ++n)
#pragma unroll
    for (int rr = 0; rr < 4; ++rr) {
      const int s = s0 + w * 16 + l16 * 4 + rr;
      const int d = n * 16 + l15;
      aob[((size_t)(b * S_ + s)) * D_ + h * DP_ + d] = f2bf(pacc[n][rr]);
    }
}

// ============================================================
extern "C" void kernel_launch(void* const* d_in, const int* in_sizes, int n_in,
                              void* d_out, int out_size, void* d_ws, size_t ws_size,
                              hipStream_t stream) {
  const float* x = (const float*)d_in[0];
  const float* wq = (const float*)d_in[1];
  const float* wk = (const float*)d_in[2];
  const float* wv = (const float*)d_in[3];
  const float* E = (const float*)d_in[4];
  const float* F = (const float*)d_in[5];
  const float* ck = (const float*)d_in[6];
  const float* bo = (const float*)d_in[9];
  const float* wo = (const float*)d_in[8];
  float* out = (float*)d_out;

  const size_t QN = (size_t)B_ * S_ * D_;   // 16M
  const size_t WN = (size_t)D_ * D_;        // 1M
  const size_t TN = (size_t)DP_ * S_ * 64;  // 16M (kT/vT)
  const size_t PN = (size_t)64 * R_ * DP_;  // 1M

  short* xb = (short*)d_ws;           // 16M [later ETb]
  short* wT = xb + QN;                // 4M
  short* qb = wT + 4 * WN;            // 16M
  short* kb = qb + QN;                // 16M [later FTb]
  short* vb = kb + QN;                // 16M [later aob]
  short* kTb = vb + QN;               // 16M
  short* vTb = kTb + TN;              // 16M
  short* kprojb = vTb + TN;           // 1M
  short* vprojTb = kprojb + PN;       // 1M
  short* Tt = vprojTb + PN;           // 196608
  short* ETb = xb;
  short* FTb = kb;
  short* aob = vb;

  convert_x_kernel<<<2048, 256, 0, stream>>>(x, xb);
  {
    dim3 g(16, 16, 4);
    transpose_w_kernel<<<g, 256, 0, stream>>>(wq, wk, wv, wo, wT);
  }
  {
    dim3 g(D_ / 128, (B_ * S_) / 128, 3);
    qkv_mfma_kernel<<<g, 256, 0, stream>>>(xb, wT, qb, kb, vb);
  }
  build_T_kernel<<<768, 256, 0, stream>>>(ck, Tt);
  {
    dim3 g(S_ / 64, B_ * H_, 2);
    transpose_kv_kernel<<<g, 256, 0, stream>>>(kb, vb, kTb, vTb);
  }
  {
    dim3 g(S_ / 64, R_ / 64, 32);
    transpose_EF_kernel<<<g, 256, 0, stream>>>(E, F, ETb, FTb);
  }
  {
    dim3 g(2, 64, 2);
    proj_mfma_kernel<<<g, 256, 0, stream>>>(ETb, FTb, kTb, vTb, kprojb, vprojTb);
  }
  {
    dim3 g(S_ / 64, B_ * H_);
    attn_fused_kernel<<<g, 256, 0, stream>>>(qb, kprojb, vprojTb, Tt, aob);
  }
  {
    dim3 g(D_ / 128, (B_ * S_) / 128);
    out_mfma_kernel<<<g, 256, 0, stream>>>(aob, wT + 3 * WN, bo, out);
  }
}

// Round 4
// 693.808 us; speedup vs baseline: 6.9475x; 1.4288x over previous
//
#include <hip/hip_runtime.h>

#define B_ 4
#define S_ 4096
#define D_ 1024
#define H_ 16
#define R_ 256
#define DP_ 64

typedef short bf16x8 __attribute__((ext_vector_type(8)));
typedef short short4v __attribute__((ext_vector_type(4)));
typedef float f32x4 __attribute__((ext_vector_type(4)));

__device__ __forceinline__ short f2bf(float f) {
  unsigned u = __builtin_bit_cast(unsigned, f);
  u += 0x7fffu + ((u >> 16) & 1u);
  return (short)(u >> 16);
}
__device__ __forceinline__ float bf2f(short s) {
  unsigned u = ((unsigned)(unsigned short)s) << 16;
  return __builtin_bit_cast(float, u);
}

// ============================================================
// x fp32 -> bf16
// ============================================================
__global__ __launch_bounds__(256) void convert_x_kernel(const float* __restrict__ x,
                                                        short* __restrict__ xb) {
  const int n8 = (B_ * S_ * D_) / 8;
  int i = blockIdx.x * 256 + threadIdx.x;
  const int stride = gridDim.x * 256;
  for (; i < n8; i += stride) {
    const float4 a = ((const float4*)x)[2 * i];
    const float4 b = ((const float4*)x)[2 * i + 1];
    bf16x8 o;
    o[0] = f2bf(a.x); o[1] = f2bf(a.y); o[2] = f2bf(a.z); o[3] = f2bf(a.w);
    o[4] = f2bf(b.x); o[5] = f2bf(b.y); o[6] = f2bf(b.z); o[7] = f2bf(b.w);
    ((bf16x8*)xb)[i] = o;
  }
}

// ============================================================
// weight [K][N] fp32 -> wT [N][K] bf16  (z selects wq/wk/wv/wo)
// ============================================================
__global__ __launch_bounds__(256) void transpose_w_kernel(
    const float* __restrict__ w0, const float* __restrict__ w1,
    const float* __restrict__ w2, const float* __restrict__ w3,
    short* __restrict__ wT) {
  __shared__ float tile[64][65];
  const int z = blockIdx.z;
  const float* W = (z == 0) ? w0 : (z == 1) ? w1 : (z == 2) ? w2 : w3;
  short* out = wT + (size_t)z * (D_ * D_);
  const int k0 = blockIdx.y * 64;
  const int n0 = blockIdx.x * 64;
  const int tid = threadIdx.x;
#pragma unroll
  for (int q = 0; q < 4; ++q) {
    const int rr = (tid >> 4) + (q << 4);
    const float4 v = *(const float4*)&W[(size_t)(k0 + rr) * D_ + n0 + ((tid & 15) << 2)];
    tile[rr][(tid & 15) * 4 + 0] = v.x;
    tile[rr][(tid & 15) * 4 + 1] = v.y;
    tile[rr][(tid & 15) * 4 + 2] = v.z;
    tile[rr][(tid & 15) * 4 + 3] = v.w;
  }
  __syncthreads();
#pragma unroll
  for (int q = 0; q < 2; ++q) {
    const int nr = (tid >> 3) + (q << 5);
    const int c8 = (tid & 7) << 3;
    bf16x8 o;
#pragma unroll
    for (int j = 0; j < 8; ++j) o[j] = f2bf(tile[c8 + j][nr]);
    *(bf16x8*)&out[(size_t)(n0 + nr) * D_ + k0 + c8] = o;
  }
}

// ============================================================
// Toeplitz: Tt[i][r][c] = ck[i*256 + (c-r+127)] * 0.125 (0 outside)
// (scale folded in; conv bias dropped — cancels in softmax)
// ============================================================
__global__ __launch_bounds__(256) void build_T_kernel(const float* __restrict__ ck,
                                                      short* __restrict__ Tt) {
  const int idx = blockIdx.x * 256 + threadIdx.x;  // 3*256*256 total
  const int i = idx >> 16;
  const int r = (idx >> 8) & 255;
  const int c = idx & 255;
  const int j = c - r + 127;
  const float v = (j >= 0 && j < 256) ? ck[i * 256 + j] * 0.125f : 0.f;
  Tt[idx] = f2bf(v);
}

// ============================================================
// bf16 MFMA GEMM: C[M][1024] = A[M][1024] @ Bt[1024][1024]^T
// ============================================================
template <bool OUT_BF16>
__device__ __forceinline__ void mfma_gemm_1024(const short* __restrict__ A,
                                               const short* __restrict__ Bt,
                                               void* __restrict__ Cout,
                                               const float* __restrict__ bias) {
  __shared__ short As[128 * 32];
  __shared__ short Bs[128 * 32];
  const int tid = threadIdx.x;
  const int w = tid >> 6, l = tid & 63;
  const int m0 = blockIdx.y * 128, n0 = blockIdx.x * 128;

  const int srow = (w << 5) + (l >> 2);
  const int gchunk = l & 3;
  const int schunkX = ((gchunk ^ (srow & 3)) << 4);
  const short* Ag = A + (size_t)(m0 + srow) * D_ + (gchunk << 3);
  const short* Bg = Bt + (size_t)(n0 + srow) * D_ + (gchunk << 3);
  char* AsW = (char*)As + srow * 64 + schunkX;
  char* BsW = (char*)Bs + srow * 64 + schunkX;

  const int wr = ((w >> 1) << 6);
  const int wc = ((w & 1) << 6);
  const int fx = (l >> 4) ^ (l & 3);

  f32x4 acc[4][4];
#pragma unroll
  for (int i = 0; i < 4; ++i)
#pragma unroll
    for (int j = 0; j < 4; ++j) acc[i][j] = (f32x4){0.f, 0.f, 0.f, 0.f};

  for (int k0 = 0; k0 < D_; k0 += 32) {
    const bf16x8 a0 = *(const bf16x8*)(Ag + k0);
    const bf16x8 a1 = *(const bf16x8*)(Ag + (size_t)16 * D_ + k0);
    const bf16x8 b0 = *(const bf16x8*)(Bg + k0);
    const bf16x8 b1 = *(const bf16x8*)(Bg + (size_t)16 * D_ + k0);
    __syncthreads();
    *(bf16x8*)AsW = a0;
    *(bf16x8*)(AsW + 1024) = a1;
    *(bf16x8*)BsW = b0;
    *(bf16x8*)(BsW + 1024) = b1;
    __syncthreads();
    bf16x8 af[4], bfv[4];
#pragma unroll
    for (int t = 0; t < 4; ++t) {
      const int ar = wr + (t << 4) + (l & 15);
      af[t] = *(const bf16x8*)((char*)As + ar * 64 + (fx << 4));
      const int br = wc + (t << 4) + (l & 15);
      bfv[t] = *(const bf16x8*)((char*)Bs + br * 64 + (fx << 4));
    }
#pragma unroll
    for (int i = 0; i < 4; ++i)
#pragma unroll
      for (int j = 0; j < 4; ++j)
        acc[i][j] = __builtin_amdgcn_mfma_f32_16x16x32_bf16(af[i], bfv[j], acc[i][j], 0, 0, 0);
  }

#pragma unroll
  for (int i = 0; i < 4; ++i) {
#pragma unroll
    for (int r = 0; r < 4; ++r) {
      const int row = m0 + wr + (i << 4) + ((l >> 4) << 2) + r;
#pragma unroll
      for (int j = 0; j < 4; ++j) {
        const int col = n0 + wc + (j << 4) + (l & 15);
        const float vv = acc[i][j][r];
        if (OUT_BF16)
          ((short*)Cout)[(size_t)row * D_ + col] = f2bf(vv);
        else
          ((float*)Cout)[(size_t)row * D_ + col] = vv + bias[col];
      }
    }
  }
}

__global__ __launch_bounds__(256) void qkv_mfma_kernel(
    const short* __restrict__ xb, const short* __restrict__ wT,
    short* __restrict__ qb, short* __restrict__ kb, short* __restrict__ vb) {
  const int z = blockIdx.z;
  const short* Bt = wT + (size_t)z * (D_ * D_);
  short* C = (z == 0) ? qb : (z == 1) ? kb : vb;
  mfma_gemm_1024<true>(xb, Bt, C, nullptr);
}

__global__ __launch_bounds__(256) void out_mfma_kernel(
    const short* __restrict__ aob, const short* __restrict__ woT,
    const float* __restrict__ bo, float* __restrict__ out) {
  mfma_gemm_1024<false>(aob, woT, out, bo);
}

// ============================================================
// k/v [b][n][h*64+d] bf16 -> kT/vT [bh][d][n] bf16 (64n x 64d tiles)
// ============================================================
__global__ __launch_bounds__(256) void transpose_kv_kernel(
    const short* __restrict__ kb, const short* __restrict__ vb,
    short* __restrict__ kTb, short* __restrict__ vTb) {
  __shared__ short tile[64 * 80];
  const int tid = threadIdx.x;
  const int n0 = blockIdx.x * 64;
  const int bh = blockIdx.y;
  const int b = bh >> 4, h = bh & 15;
  const short* src = blockIdx.z ? vb : kb;
  short* dst = blockIdx.z ? vTb : kTb;
#pragma unroll
  for (int q = 0; q < 2; ++q) {
    const int idx = tid + q * 256;
    const int n = idx >> 3, c = idx & 7;
    *(bf16x8*)&tile[n * 80 + c * 8] =
        *(const bf16x8*)&src[((size_t)b * S_ + n0 + n) * D_ + h * DP_ + c * 8];
  }
  __syncthreads();
#pragma unroll
  for (int q = 0; q < 2; ++q) {
    const int idx = tid + q * 256;
    const int d = idx >> 3, cc = idx & 7;
    bf16x8 o;
#pragma unroll
    for (int j = 0; j < 8; ++j) o[j] = tile[(cc * 8 + j) * 80 + d];
    *(bf16x8*)&dst[((size_t)bh * DP_ + d) * S_ + n0 + cc * 8] = o;
  }
}

// ============================================================
// E/F fp32 [h][n][r] -> ET/FT bf16 [h][r][n] (64n x 64r tiles)
// ============================================================
__global__ __launch_bounds__(256) void transpose_EF_kernel(
    const float* __restrict__ E, const float* __restrict__ F,
    short* __restrict__ ETb, short* __restrict__ FTb) {
  __shared__ float tile[64][65];
  const int tid = threadIdx.x;
  const int n0 = blockIdx.x * 64;
  const int r0 = blockIdx.y * 64;
  const int hz = blockIdx.z;
  const int h = hz & 15;
  const float* src = (hz < 16) ? E : F;
  short* dst = (hz < 16) ? ETb : FTb;
  const float* base = src + ((size_t)h * S_ + n0) * R_ + r0;
#pragma unroll
  for (int q = 0; q < 4; ++q) {
    const int n = (tid >> 4) + q * 16;
    const int r4 = (tid & 15) << 2;
    const float4 v = *(const float4*)&base[(size_t)n * R_ + r4];
    tile[n][r4 + 0] = v.x; tile[n][r4 + 1] = v.y;
    tile[n][r4 + 2] = v.z; tile[n][r4 + 3] = v.w;
  }
  __syncthreads();
#pragma unroll
  for (int q = 0; q < 2; ++q) {
    const int r = (tid >> 3) + q * 32;
    const int n8 = (tid & 7) << 3;
    bf16x8 o;
#pragma unroll
    for (int j = 0; j < 8; ++j) o[j] = f2bf(tile[n8 + j][r]);
    *(bf16x8*)&dst[((size_t)h * R_ + r0 + r) * S_ + n0 + n8] = o;
  }
}

// ============================================================
// proj MFMA: per (bh): C[128r x 64d] = ET[128r][4096n] @ kT[64d][4096n]^T
// grid (2 rhalf, 64 bh, 2 z). Both outputs TRANSPOSED: [bh][d][r]
// z=0 -> kprojTb ; z=1 -> vprojTb
// ============================================================
__global__ __launch_bounds__(256) void proj_mfma_kernel(
    const short* __restrict__ ETb, const short* __restrict__ FTb,
    const short* __restrict__ kTb, const short* __restrict__ vTb,
    short* __restrict__ kprojTb, short* __restrict__ vprojTb) {
  __shared__ short As[128 * 64];
  __shared__ short Bs[64 * 64];
  const int tid = threadIdx.x;
  const int w = tid >> 6, l = tid & 63;
  const int l15 = l & 15, l16 = l >> 4;
  const int r0 = blockIdx.x * 128;
  const int bh = blockIdx.y;
  const int h = bh & 15;
  const int z = blockIdx.z;
  const short* Ab = (z ? FTb : ETb) + ((size_t)h * R_ + r0) * S_;
  const short* Bb = (z ? vTb : kTb) + (size_t)bh * DP_ * S_;
  short* outp = z ? vprojTb : kprojTb;
  const int wm = w >> 1, wn = w & 1;

  f32x4 acc[4][2];
#pragma unroll
  for (int mt = 0; mt < 4; ++mt)
#pragma unroll
    for (int nt = 0; nt < 2; ++nt) acc[mt][nt] = (f32x4){0.f, 0.f, 0.f, 0.f};

  for (int k0 = 0; k0 < S_; k0 += 64) {
    bf16x8 a[4], bq[2];
#pragma unroll
    for (int j = 0; j < 4; ++j) {
      const int idx = tid + j * 256;
      const int ar = idx >> 3, c = idx & 7;
      a[j] = *(const bf16x8*)&Ab[(size_t)ar * S_ + k0 + c * 8];
    }
#pragma unroll
    for (int j = 0; j < 2; ++j) {
      const int idx = tid + j * 256;
      const int br = idx >> 3, c = idx & 7;
      bq[j] = *(const bf16x8*)&Bb[(size_t)br * S_ + k0 + c * 8];
    }
    __syncthreads();
#pragma unroll
    for (int j = 0; j < 4; ++j) {
      const int idx = tid + j * 256;
      const int ar = idx >> 3, c = idx & 7;
      *(bf16x8*)((char*)As + ar * 128 + ((c ^ (ar & 7)) << 4)) = a[j];
    }
#pragma unroll
    for (int j = 0; j < 2; ++j) {
      const int idx = tid + j * 256;
      const int br = idx >> 3, c = idx & 7;
      *(bf16x8*)((char*)Bs + br * 128 + ((c ^ (br & 7)) << 4)) = bq[j];
    }
    __syncthreads();
#pragma unroll
    for (int kk = 0; kk < 2; ++kk) {
      bf16x8 af[4], bfr[2];
#pragma unroll
      for (int mt = 0; mt < 4; ++mt) {
        const int row = wm * 64 + mt * 16 + l15;
        af[mt] = *(const bf16x8*)((char*)As + row * 128 + (((kk * 4 + l16) ^ (row & 7)) << 4));
      }
#pragma unroll
      for (int nt = 0; nt < 2; ++nt) {
        const int row = wn * 32 + nt * 16 + l15;
        bfr[nt] = *(const bf16x8*)((char*)Bs + row * 128 + (((kk * 4 + l16) ^ (row & 7)) << 4));
      }
#pragma unroll
      for (int mt = 0; mt < 4; ++mt)
#pragma unroll
        for (int nt = 0; nt < 2; ++nt)
          acc[mt][nt] = __builtin_amdgcn_mfma_f32_16x16x32_bf16(af[mt], bfr[nt], acc[mt][nt], 0, 0, 0);
    }
  }

#pragma unroll
  for (int mt = 0; mt < 4; ++mt)
#pragma unroll
    for (int nt = 0; nt < 2; ++nt) {
      const int d = wn * 32 + nt * 16 + l15;
      const int rbase = r0 + wm * 64 + mt * 16 + l16 * 4;
      short4v o;
#pragma unroll
      for (int rr = 0; rr < 4; ++rr) o[rr] = f2bf(acc[mt][nt][rr]);
      *(short4v*)&outp[((size_t)bh * DP_ + d) * R_ + rbase] = o;
    }
}

// ============================================================
// build_M: M[bh][i][r][d] = sum_c Tt[i][r][c] * kprojT[bh][d][c]
// grid (4 rquarter, 64 bh), 256 thr; wave w -> rows r0=bx*64+w*16
// ============================================================
__global__ __launch_bounds__(256) void build_M_kernel(
    const short* __restrict__ Tt, const short* __restrict__ kprojTb,
    short* __restrict__ Mb) {
  const int tid = threadIdx.x;
  const int w = tid >> 6, l = tid & 63;
  const int l15 = l & 15, l16 = l >> 4;
  const int r0 = blockIdx.x * 64 + w * 16;
  const int bh = blockIdx.y;
  const short* Kp = kprojTb + (size_t)bh * DP_ * R_;

#pragma unroll
  for (int i = 0; i < 3; ++i) {
    const short* Ti = Tt + (size_t)i * (R_ * R_);
    f32x4 acc[4];
#pragma unroll
    for (int n = 0; n < 4; ++n) acc[n] = (f32x4){0.f, 0.f, 0.f, 0.f};
#pragma unroll
    for (int kk = 0; kk < 8; ++kk) {
      const bf16x8 av = *(const bf16x8*)&Ti[(size_t)(r0 + l15) * R_ + kk * 32 + l16 * 8];
#pragma unroll
      for (int n = 0; n < 4; ++n) {
        const bf16x8 bv = *(const bf16x8*)&Kp[(size_t)(n * 16 + l15) * R_ + kk * 32 + l16 * 8];
        acc[n] = __builtin_amdgcn_mfma_f32_16x16x32_bf16(av, bv, acc[n], 0, 0, 0);
      }
    }
    short* Mo = Mb + (((size_t)bh * 3 + i) * R_) * DP_;
#pragma unroll
    for (int n = 0; n < 4; ++n)
#pragma unroll
      for (int rr = 0; rr < 4; ++rr)
        Mo[(size_t)(r0 + l16 * 4 + rr) * DP_ + n * 16 + l15] = f2bf(acc[n][rr]);
  }
}

// ============================================================
// Fused attn: convscores[t][r] = sum_i q[t-1+i] . M_i[r]  (MFMA, K=192)
//   -> softmax (4-row-parallel) -> PV (MFMA) -> aob bf16
// grid (S/64=64, BH=64), 256 threads (4 waves)
// LDS: P [64][256] bf16 swizzled (32768B) + q [66 rows][144B] (9504B)
// ============================================================
__global__ __launch_bounds__(256) void attn_fused_kernel(
    const short* __restrict__ qb, const short* __restrict__ Mb,
    const short* __restrict__ vprojTb, short* __restrict__ aob) {
  __shared__ char smem[32768 + 66 * 144];
  const int tid = threadIdx.x;
  const int w = tid >> 6, l = tid & 63;
  const int l15 = l & 15, l16 = l >> 4;
  const int s0 = blockIdx.x * 64;
  const int bh = blockIdx.y;
  const int b = bh >> 4, h = bh & 15;

  // stage q rows s0-1 .. s0+64 (66 rows x 64d), row stride 144B (16B pad)
  for (int idx = tid; idx < 66 * 8; idx += 256) {
    const int t = idx >> 3, c = idx & 7;
    const int s = s0 - 1 + t;
    bf16x8 val = {0, 0, 0, 0, 0, 0, 0, 0};
    if (s >= 0 && s < S_)
      val = *(const bf16x8*)&qb[((size_t)(b * S_ + s)) * D_ + h * DP_ + c * 8];
    *(bf16x8*)(smem + 32768 + t * 144 + c * 16) = val;
  }
  __syncthreads();

  // ---- phase A: logits[t][r] = sum_i q[t-1+i] . M_i[r], wave w: cols w*64.. ----
  f32x4 acc[4][4];
#pragma unroll
  for (int m = 0; m < 4; ++m)
#pragma unroll
    for (int n = 0; n < 4; ++n) acc[m][n] = (f32x4){0.f, 0.f, 0.f, 0.f};

  const short* Mbh = Mb + (size_t)bh * 3 * R_ * DP_;
#pragma unroll
  for (int i = 0; i < 3; ++i) {
    bf16x8 qf[4][2];
#pragma unroll
    for (int m = 0; m < 4; ++m)
#pragma unroll
      for (int kk = 0; kk < 2; ++kk)
        qf[m][kk] = *(const bf16x8*)(smem + 32768 + (m * 16 + l15 + i) * 144 +
                                     ((kk * 4 + l16) << 4));
    const short* Mi = Mbh + (size_t)i * R_ * DP_;
#pragma unroll
    for (int n = 0; n < 4; ++n) {
      const short* mrow = Mi + (size_t)(w * 64 + n * 16 + l15) * DP_ + l16 * 8;
      const bf16x8 m0 = *(const bf16x8*)mrow;
      const bf16x8 m1 = *(const bf16x8*)(mrow + 32);
#pragma unroll
      for (int m = 0; m < 4; ++m) {
        acc[m][n] = __builtin_amdgcn_mfma_f32_16x16x32_bf16(qf[m][0], m0, acc[m][n], 0, 0, 0);
        acc[m][n] = __builtin_amdgcn_mfma_f32_16x16x32_bf16(qf[m][1], m1, acc[m][n], 0, 0, 0);
      }
    }
  }
  // write logits -> P LDS (bf16, chunk-XOR swizzled)
#pragma unroll
  for (int m = 0; m < 4; ++m)
#pragma unroll
    for (int n = 0; n < 4; ++n)
#pragma unroll
      for (int rr = 0; rr < 4; ++rr) {
        const int t = m * 16 + l16 * 4 + rr;
        const int c = w * 64 + n * 16 + l15;
        const int off = t * 512 + (((c >> 3) ^ (t & 7)) << 4) + ((c & 7) << 1);
        *(short*)(smem + off) = f2bf(acc[m][n][rr]);
      }
  __syncthreads();

  // ---- phase B: softmax, 4 rows in parallel (16-lane groups) ----
  {
    const int g = l >> 4, u = l & 15;
#pragma unroll
    for (int it = 0; it < 4; ++it) {
      const int t = w * 16 + it * 4 + g;
      const int off0 = t * 512 + (((u * 2) ^ (t & 7)) << 4);
      const int off1 = t * 512 + (((u * 2 + 1) ^ (t & 7)) << 4);
      bf16x8 p0 = *(bf16x8*)(smem + off0);
      bf16x8 p1 = *(bf16x8*)(smem + off1);
      float f[16];
#pragma unroll
      for (int j = 0; j < 8; ++j) { f[j] = bf2f(p0[j]); f[8 + j] = bf2f(p1[j]); }
      float mx = f[0];
#pragma unroll
      for (int j = 1; j < 16; ++j) mx = fmaxf(mx, f[j]);
#pragma unroll
      for (int d = 1; d < 16; d <<= 1) mx = fmaxf(mx, __shfl_xor(mx, d, 64));
      float sm = 0.f;
#pragma unroll
      for (int j = 0; j < 16; ++j) { f[j] = __expf(f[j] - mx); sm += f[j]; }
#pragma unroll
      for (int d = 1; d < 16; d <<= 1) sm += __shfl_xor(sm, d, 64);
      const float inv = 1.f / sm;
#pragma unroll
      for (int j = 0; j < 8; ++j) { p0[j] = f2bf(f[j] * inv); p1[j] = f2bf(f[8 + j] * inv); }
      *(bf16x8*)(smem + off0) = p0;
      *(bf16x8*)(smem + off1) = p1;
    }
  }
  __syncthreads();

  // ---- phase C: PV. out[64][64] = P[64][256] @ vprojT[64][256]^T ----
  f32x4 pacc[4];
#pragma unroll
  for (int n = 0; n < 4; ++n) pacc[n] = (f32x4){0.f, 0.f, 0.f, 0.f};
#pragma unroll
  for (int kk = 0; kk < 8; ++kk) {
    const int row = w * 16 + l15;
    const int ck = kk * 4 + l16;
    const bf16x8 pa = *(const bf16x8*)(smem + row * 512 + ((ck ^ (row & 7)) << 4));
#pragma unroll
    for (int n = 0; n < 4; ++n) {
      const bf16x8 bv = *(const bf16x8*)(vprojTb + ((size_t)bh * DP_ + n * 16 + l15) * R_ +
                                         (kk << 5) + (l16 << 3));
      pacc[n] = __builtin_amdgcn_mfma_f32_16x16x32_bf16(pa, bv, pacc[n], 0, 0, 0);
    }
  }
#pragma unroll
  for (int n = 0; n < 4; ++n)
#pragma unroll
    for (int rr = 0; rr < 4; ++rr) {
      const int s = s0 + w * 16 + l16 * 4 + rr;
      const int d = n * 16 + l15;
      aob[((size_t)(b * S_ + s)) * D_ + h * DP_ + d] = f2bf(pacc[n][rr]);
    }
}

// ============================================================
extern "C" void kernel_launch(void* const* d_in, const int* in_sizes, int n_in,
                              void* d_out, int out_size, void* d_ws, size_t ws_size,
                              hipStream_t stream) {
  const float* x = (const float*)d_in[0];
  const float* wq = (const float*)d_in[1];
  const float* wk = (const float*)d_in[2];
  const float* wv = (const float*)d_in[3];
  const float* E = (const float*)d_in[4];
  const float* F = (const float*)d_in[5];
  const float* ck = (const float*)d_in[6];
  const float* wo = (const float*)d_in[8];
  const float* bo = (const float*)d_in[9];
  float* out = (float*)d_out;

  const size_t QN = (size_t)B_ * S_ * D_;   // 16M
  const size_t WN = (size_t)D_ * D_;        // 1M
  const size_t TN = (size_t)DP_ * S_ * 64;  // 16M (kT/vT)
  const size_t PN = (size_t)64 * R_ * DP_;  // 1M

  short* xb = (short*)d_ws;           // 16M [later ETb, then Mb(3M)]
  short* wT = xb + QN;                // 4M
  short* qb = wT + 4 * WN;            // 16M
  short* kb = qb + QN;                // 16M [later FTb]
  short* vb = kb + QN;                // 16M [later aob]
  short* kTb = vb + QN;               // 16M
  short* vTb = kTb + TN;              // 16M
  short* kprojTb = vTb + TN;          // 1M
  short* vprojTb = kprojTb + PN;      // 1M
  short* Tt = vprojTb + PN;           // 196608
  short* ETb = xb;
  short* FTb = kb;
  short* Mb = xb;
  short* aob = vb;

  convert_x_kernel<<<2048, 256, 0, stream>>>(x, xb);
  {
    dim3 g(16, 16, 4);
    transpose_w_kernel<<<g, 256, 0, stream>>>(wq, wk, wv, wo, wT);
  }
  {
    dim3 g(D_ / 128, (B_ * S_) / 128, 3);
    qkv_mfma_kernel<<<g, 256, 0, stream>>>(xb, wT, qb, kb, vb);
  }
  build_T_kernel<<<768, 256, 0, stream>>>(ck, Tt);
  {
    dim3 g(S_ / 64, B_ * H_, 2);
    transpose_kv_kernel<<<g, 256, 0, stream>>>(kb, vb, kTb, vTb);
  }
  {
    dim3 g(S_ / 64, R_ / 64, 32);
    transpose_EF_kernel<<<g, 256, 0, stream>>>(E, F, ETb, FTb);
  }
  {
    dim3 g(2, 64, 2);
    proj_mfma_kernel<<<g, 256, 0, stream>>>(ETb, FTb, kTb, vTb, kprojTb, vprojTb);
  }
  {
    dim3 g(4, 64);
    build_M_kernel<<<g, 256, 0, stream>>>(Tt, kprojTb, Mb);
  }
  {
    dim3 g(S_ / 64, B_ * H_);
    attn_fused_kernel<<<g, 256, 0, stream>>>(qb, Mb, vprojTb, aob);
  }
  {
    dim3 g(D_ / 128, (B_ * S_) / 128);
    out_mfma_kernel<<<g, 256, 0, stream>>>(aob, wT + 3 * WN, bo, out);
  }
}

// Round 6
// 657.076 us; speedup vs baseline: 7.3359x; 1.0559x over previous
//
#include <hip/hip_runtime.h>

#define B_ 4
#define S_ 4096
#define D_ 1024
#define H_ 16
#define R_ 256
#define DP_ 64

typedef short bf16x8 __attribute__((ext_vector_type(8)));
typedef short short4v __attribute__((ext_vector_type(4)));
typedef float f32x4 __attribute__((ext_vector_type(4)));
typedef unsigned int u32;

__device__ __forceinline__ short f2bf(float f) {
  unsigned u = __builtin_bit_cast(unsigned, f);
  u += 0x7fffu + ((u >> 16) & 1u);
  return (short)(u >> 16);
}
__device__ __forceinline__ float bf2f(short s) {
  unsigned u = ((unsigned)(unsigned short)s) << 16;
  return __builtin_bit_cast(float, u);
}

// async global->LDS, 16B per lane; lds base must be wave-uniform
__device__ __forceinline__ void gload16(const short* g, short* l) {
  __builtin_amdgcn_global_load_lds((const __attribute__((address_space(1))) u32*)g,
                                   (__attribute__((address_space(3))) u32*)l, 16, 0, 0);
}

// ============================================================
// x fp32 -> bf16
// ============================================================
__global__ __launch_bounds__(256) void convert_x_kernel(const float* __restrict__ x,
                                                        short* __restrict__ xb) {
  const int n8 = (B_ * S_ * D_) / 8;
  int i = blockIdx.x * 256 + threadIdx.x;
  const int stride = gridDim.x * 256;
  for (; i < n8; i += stride) {
    const float4 a = ((const float4*)x)[2 * i];
    const float4 b = ((const float4*)x)[2 * i + 1];
    bf16x8 o;
    o[0] = f2bf(a.x); o[1] = f2bf(a.y); o[2] = f2bf(a.z); o[3] = f2bf(a.w);
    o[4] = f2bf(b.x); o[5] = f2bf(b.y); o[6] = f2bf(b.z); o[7] = f2bf(b.w);
    ((bf16x8*)xb)[i] = o;
  }
}

// ============================================================
// weight [K][N] fp32 -> wT [N][K] bf16  (z selects wq/wk/wv/wo)
// ============================================================
__global__ __launch_bounds__(256) void transpose_w_kernel(
    const float* __restrict__ w0, const float* __restrict__ w1,
    const float* __restrict__ w2, const float* __restrict__ w3,
    short* __restrict__ wT) {
  __shared__ float tile[64][65];
  const int z = blockIdx.z;
  const float* W = (z == 0) ? w0 : (z == 1) ? w1 : (z == 2) ? w2 : w3;
  short* out = wT + (size_t)z * (D_ * D_);
  const int k0 = blockIdx.y * 64;
  const int n0 = blockIdx.x * 64;
  const int tid = threadIdx.x;
#pragma unroll
  for (int q = 0; q < 4; ++q) {
    const int rr = (tid >> 4) + (q << 4);
    const float4 v = *(const float4*)&W[(size_t)(k0 + rr) * D_ + n0 + ((tid & 15) << 2)];
    tile[rr][(tid & 15) * 4 + 0] = v.x;
    tile[rr][(tid & 15) * 4 + 1] = v.y;
    tile[rr][(tid & 15) * 4 + 2] = v.z;
    tile[rr][(tid & 15) * 4 + 3] = v.w;
  }
  __syncthreads();
#pragma unroll
  for (int q = 0; q < 2; ++q) {
    const int nr = (tid >> 3) + (q << 5);
    const int c8 = (tid & 7) << 3;
    bf16x8 o;
#pragma unroll
    for (int j = 0; j < 8; ++j) o[j] = f2bf(tile[c8 + j][nr]);
    *(bf16x8*)&out[(size_t)(n0 + nr) * D_ + k0 + c8] = o;
  }
}

// ============================================================
// Toeplitz: Tt[i][r][c] = ck[i*256 + (c-r+127)] * 0.125 (0 outside)
// ============================================================
__global__ __launch_bounds__(256) void build_T_kernel(const float* __restrict__ ck,
                                                      short* __restrict__ Tt) {
  const int idx = blockIdx.x * 256 + threadIdx.x;  // 3*256*256 total
  const int i = idx >> 16;
  const int r = (idx >> 8) & 255;
  const int c = idx & 255;
  const int j = c - r + 127;
  const float v = (j >= 0 && j < 256) ? ck[i * 256 + j] * 0.125f : 0.f;
  Tt[idx] = f2bf(v);
}

// ============================================================
// core MFMA GEMM tile: acc[4][4] for C-tile (m0,n0), K=1024.
// A [M][1024], Bt [N][1024] bf16 row-major. m97-style gload_lds staging.
// 128x128 tile, BK=32, 4 waves, 64x64/wave.
// ============================================================
__device__ __forceinline__ void gemm_core_1024(const short* __restrict__ A,
                                               const short* __restrict__ Bt,
                                               int m0, int n0, f32x4 acc[4][4]) {
  __shared__ short As[128 * 32];
  __shared__ short Bs[128 * 32];
  const int tid = threadIdx.x;
  const int w = tid >> 6, l = tid & 63;
  const int l15 = l & 15, l16 = l >> 4;
  const int wr = (w >> 1) << 6, wc = (w & 1) << 6;

  // wave w stages rows w*32..w*32+31 of each tile (2 calls of 16 rows)
  const short* Ag = A + (size_t)(m0 + w * 32 + (l >> 2)) * D_ + (l & 3) * 8;
  const short* Bg = Bt + (size_t)(n0 + w * 32 + (l >> 2)) * D_ + (l & 3) * 8;
  short* AsD = As + w * 1024;  // wave-uniform LDS base
  short* BsD = Bs + w * 1024;

  for (int k0 = 0; k0 < D_; k0 += 32) {
    __syncthreads();
    gload16(Ag + k0, AsD);
    gload16(Ag + k0 + 16 * D_, AsD + 512);
    gload16(Bg + k0, BsD);
    gload16(Bg + k0 + 16 * D_, BsD + 512);
    __syncthreads();
    bf16x8 af[4], bv[4];
#pragma unroll
    for (int t = 0; t < 4; ++t) {
      af[t] = *(const bf16x8*)(As + (wr + t * 16 + l15) * 32 + l16 * 8);
      bv[t] = *(const bf16x8*)(Bs + (wc + t * 16 + l15) * 32 + l16 * 8);
    }
#pragma unroll
    for (int i = 0; i < 4; ++i)
#pragma unroll
      for (int j = 0; j < 4; ++j)
        acc[i][j] = __builtin_amdgcn_mfma_f32_16x16x32_bf16(af[i], bv[j], acc[i][j], 0, 0, 0);
  }
}

// ============================================================
// merged QKV: C[16384][3072] = x @ [wq|wk|wv]^T
// cols 0..1023 -> qb row-major; 1024..2047 -> kT [bh][d][n]; 2048.. -> vT
// grid 3072 blocks 1D, bijective XCD swizzle (chunk 384)
// ============================================================
__global__ __launch_bounds__(256) void qkv_mfma_kernel(
    const short* __restrict__ xb, const short* __restrict__ wT,
    short* __restrict__ qb, short* __restrict__ kTb, short* __restrict__ vTb) {
  const int wg = blockIdx.x;
  const int swz = (wg & 7) * 384 + (wg >> 3);
  const int nx = swz % 24, my = swz / 24;
  const int m0 = my * 128, n0 = nx * 128;

  f32x4 acc[4][4];
#pragma unroll
  for (int i = 0; i < 4; ++i)
#pragma unroll
    for (int j = 0; j < 4; ++j) acc[i][j] = (f32x4){0.f, 0.f, 0.f, 0.f};
  gemm_core_1024(xb, wT, m0, n0, acc);

  const int tid = threadIdx.x;
  const int w = tid >> 6, l = tid & 63;
  const int l15 = l & 15, l16 = l >> 4;
  const int wr = (w >> 1) << 6, wc = (w & 1) << 6;

  if (n0 < 1024) {
#pragma unroll
    for (int i = 0; i < 4; ++i)
#pragma unroll
      for (int j = 0; j < 4; ++j)
#pragma unroll
        for (int rr = 0; rr < 4; ++rr) {
          const int row = m0 + wr + i * 16 + l16 * 4 + rr;
          const int col = n0 + wc + j * 16 + l15;
          qb[(size_t)row * D_ + col] = f2bf(acc[i][j][rr]);
        }
  } else {
    short* dst = (n0 < 2048) ? kTb : vTb;
    const int cb = n0 - ((n0 < 2048) ? 1024 : 2048);
#pragma unroll
    for (int i = 0; i < 4; ++i)
#pragma unroll
      for (int j = 0; j < 4; ++j) {
        const int col = cb + wc + j * 16 + l15;  // 0..1023
        const int h = col >> 6, d = col & 63;
        const int rowb = m0 + wr + i * 16 + l16 * 4;
        const int b = rowb >> 12, nseq = rowb & 4095;
        short4v o;
#pragma unroll
        for (int rr = 0; rr < 4; ++rr) o[rr] = f2bf(acc[i][j][rr]);
        *(short4v*)&dst[(((size_t)(b * 16 + h) * 64 + d) << 12) + nseq] = o;
      }
  }
}

// ============================================================
// out GEMM: out[16384][1024] fp32 = aob @ woT^T + bo
// grid 1024 blocks 1D, XCD swizzle (chunk 128)
// ============================================================
__global__ __launch_bounds__(256) void out_mfma_kernel(
    const short* __restrict__ aob, const short* __restrict__ woT,
    const float* __restrict__ bo, float* __restrict__ out) {
  const int wg = blockIdx.x;
  const int swz = (wg & 7) * 128 + (wg >> 3);
  const int nx = swz & 7, my = swz >> 3;
  const int m0 = my * 128, n0 = nx * 128;

  f32x4 acc[4][4];
#pragma unroll
  for (int i = 0; i < 4; ++i)
#pragma unroll
    for (int j = 0; j < 4; ++j) acc[i][j] = (f32x4){0.f, 0.f, 0.f, 0.f};
  gemm_core_1024(aob, woT, m0, n0, acc);

  const int tid = threadIdx.x;
  const int w = tid >> 6, l = tid & 63;
  const int l15 = l & 15, l16 = l >> 4;
  const int wr = (w >> 1) << 6, wc = (w & 1) << 6;
#pragma unroll
  for (int i = 0; i < 4; ++i)
#pragma unroll
    for (int j = 0; j < 4; ++j) {
      const int col = n0 + wc + j * 16 + l15;
      const float bb = bo[col];
#pragma unroll
      for (int rr = 0; rr < 4; ++rr) {
        const int row = m0 + wr + i * 16 + l16 * 4 + rr;
        out[(size_t)row * D_ + col] = acc[i][j][rr] + bb;
      }
    }
}

// ============================================================
// E/F fp32 [h][n][r] -> ET/FT bf16 [h][r][n] (64n x 64r tiles)
// ============================================================
__global__ __launch_bounds__(256) void transpose_EF_kernel(
    const float* __restrict__ E, const float* __restrict__ F,
    short* __restrict__ ETb, short* __restrict__ FTb) {
  __shared__ float tile[64][65];
  const int tid = threadIdx.x;
  const int n0 = blockIdx.x * 64;
  const int r0 = blockIdx.y * 64;
  const int hz = blockIdx.z;
  const int h = hz & 15;
  const float* src = (hz < 16) ? E : F;
  short* dst = (hz < 16) ? ETb : FTb;
  const float* base = src + ((size_t)h * S_ + n0) * R_ + r0;
#pragma unroll
  for (int q = 0; q < 4; ++q) {
    const int n = (tid >> 4) + q * 16;
    const int r4 = (tid & 15) << 2;
    const float4 v = *(const float4*)&base[(size_t)n * R_ + r4];
    tile[n][r4 + 0] = v.x; tile[n][r4 + 1] = v.y;
    tile[n][r4 + 2] = v.z; tile[n][r4 + 3] = v.w;
  }
  __syncthreads();
#pragma unroll
  for (int q = 0; q < 2; ++q) {
    const int r = (tid >> 3) + q * 32;
    const int n8 = (tid & 7) << 3;
    bf16x8 o;
#pragma unroll
    for (int j = 0; j < 8; ++j) o[j] = f2bf(tile[n8 + j][r]);
    *(bf16x8*)&dst[((size_t)h * R_ + r0 + r) * S_ + n0 + n8] = o;
  }
}

// ============================================================
// proj MFMA: per (bh): C[128r x 64d] = ET[128r][4096n] @ kT[64d][4096n]^T
// grid (2 rhalf, 64 y=h*4+b, 2 z). Outputs transposed: [bh][d][r]
// ============================================================
__global__ __launch_bounds__(256) void proj_mfma_kernel(
    const short* __restrict__ ETb, const short* __restrict__ FTb,
    const short* __restrict__ kTb, const short* __restrict__ vTb,
    short* __restrict__ kprojTb, short* __restrict__ vprojTb) {
  __shared__ short As[128 * 64];
  __shared__ short Bs[64 * 64];
  const int tid = threadIdx.x;
  const int w = tid >> 6, l = tid & 63;
  const int l15 = l & 15, l16 = l >> 4;
  const int r0 = blockIdx.x * 128;
  const int y = blockIdx.y;
  const int h = y >> 2, b = y & 3;      // h-major: 4 b's of same h adjacent
  const int bh = b * 16 + h;
  const int z = blockIdx.z;
  const short* Ab = (z ? FTb : ETb) + ((size_t)h * R_ + r0) * S_;
  const short* Bb = (z ? vTb : kTb) + (size_t)bh * DP_ * S_;
  short* outp = z ? vprojTb : kprojTb;
  const int wm = w >> 1, wn = w & 1;

  f32x4 acc[4][2];
#pragma unroll
  for (int mt = 0; mt < 4; ++mt)
#pragma unroll
    for (int nt = 0; nt < 2; ++nt) acc[mt][nt] = (f32x4){0.f, 0.f, 0.f, 0.f};

  for (int k0 = 0; k0 < S_; k0 += 64) {
    bf16x8 a[4], bq[2];
#pragma unroll
    for (int j = 0; j < 4; ++j) {
      const int idx = tid + j * 256;
      const int ar = idx >> 3, c = idx & 7;
      a[j] = *(const bf16x8*)&Ab[(size_t)ar * S_ + k0 + c * 8];
    }
#pragma unroll
    for (int j = 0; j < 2; ++j) {
      const int idx = tid + j * 256;
      const int br = idx >> 3, c = idx & 7;
      bq[j] = *(const bf16x8*)&Bb[(size_t)br * S_ + k0 + c * 8];
    }
    __syncthreads();
#pragma unroll
    for (int j = 0; j < 4; ++j) {
      const int idx = tid + j * 256;
      const int ar = idx >> 3, c = idx & 7;
      *(bf16x8*)((char*)As + ar * 128 + ((c ^ (ar & 7)) << 4)) = a[j];
    }
#pragma unroll
    for (int j = 0; j < 2; ++j) {
      const int idx = tid + j * 256;
      const int br = idx >> 3, c = idx & 7;
      *(bf16x8*)((char*)Bs + br * 128 + ((c ^ (br & 7)) << 4)) = bq[j];
    }
    __syncthreads();
#pragma unroll
    for (int kk = 0; kk < 2; ++kk) {
      bf16x8 af[4], bfr[2];
#pragma unroll
      for (int mt = 0; mt < 4; ++mt) {
        const int row = wm * 64 + mt * 16 + l15;
        af[mt] = *(const bf16x8*)((char*)As + row * 128 + (((kk * 4 + l16) ^ (row & 7)) << 4));
      }
#pragma unroll
      for (int nt = 0; nt < 2; ++nt) {
        const int row = wn * 32 + nt * 16 + l15;
        bfr[nt] = *(const bf16x8*)((char*)Bs + row * 128 + (((kk * 4 + l16) ^ (row & 7)) << 4));
      }
#pragma unroll
      for (int mt = 0; mt < 4; ++mt)
#pragma unroll
        for (int nt = 0; nt < 2; ++nt)
          acc[mt][nt] = __builtin_amdgcn_mfma_f32_16x16x32_bf16(af[mt], bfr[nt], acc[mt][nt], 0, 0, 0);
    }
  }

#pragma unroll
  for (int mt = 0; mt < 4; ++mt)
#pragma unroll
    for (int nt = 0; nt < 2; ++nt) {
      const int d = wn * 32 + nt * 16 + l15;
      const int rbase = r0 + wm * 64 + mt * 16 + l16 * 4;
      short4v o;
#pragma unroll
      for (int rr = 0; rr < 4; ++rr) o[rr] = f2bf(acc[mt][nt][rr]);
      *(short4v*)&outp[((size_t)bh * DP_ + d) * R_ + rbase] = o;
    }
}

// ============================================================
// build_M: M[bh][i][r][d] = sum_c Tt[i][r][c] * kprojT[bh][d][c]
// ============================================================
__global__ __launch_bounds__(256) void build_M_kernel(
    const short* __restrict__ Tt, const short* __restrict__ kprojTb,
    short* __restrict__ Mb) {
  const int tid = threadIdx.x;
  const int w = tid >> 6, l = tid & 63;
  const int l15 = l & 15, l16 = l >> 4;
  const int r0 = blockIdx.x * 64 + w * 16;
  const int bh = blockIdx.y;
  const short* Kp = kprojTb + (size_t)bh * DP_ * R_;

#pragma unroll
  for (int i = 0; i < 3; ++i) {
    const short* Ti = Tt + (size_t)i * (R_ * R_);
    f32x4 acc[4];
#pragma unroll
    for (int n = 0; n < 4; ++n) acc[n] = (f32x4){0.f, 0.f, 0.f, 0.f};
#pragma unroll
    for (int kk = 0; kk < 8; ++kk) {
      const bf16x8 av = *(const bf16x8*)&Ti[(size_t)(r0 + l15) * R_ + kk * 32 + l16 * 8];
#pragma unroll
      for (int n = 0; n < 4; ++n) {
        const bf16x8 bv = *(const bf16x8*)&Kp[(size_t)(n * 16 + l15) * R_ + kk * 32 + l16 * 8];
        acc[n] = __builtin_amdgcn_mfma_f32_16x16x32_bf16(av, bv, acc[n], 0, 0, 0);
      }
    }
    short* Mo = Mb + (((size_t)bh * 3 + i) * R_) * DP_;
#pragma unroll
    for (int n = 0; n < 4; ++n)
#pragma unroll
      for (int rr = 0; rr < 4; ++rr)
        Mo[(size_t)(r0 + l16 * 4 + rr) * DP_ + n * 16 + l15] = f2bf(acc[n][rr]);
  }
}

// ============================================================
// Fused attn: logits[t][r] = sum_i q[t-1+i] . M_i[r]  (MFMA, K=192)
//   -> softmax (4-row-parallel) -> PV (MFMA) -> aob bf16
// ============================================================
__global__ __launch_bounds__(256) void attn_fused_kernel(
    const short* __restrict__ qb, const short* __restrict__ Mb,
    const short* __restrict__ vprojTb, short* __restrict__ aob) {
  __shared__ char smem[32768 + 66 * 144];
  const int tid = threadIdx.x;
  const int w = tid >> 6, l = tid & 63;
  const int l15 = l & 15, l16 = l >> 4;
  const int s0 = blockIdx.x * 64;
  const int bh = blockIdx.y;
  const int b = bh >> 4, h = bh & 15;

  // stage q rows s0-1 .. s0+64 (66 rows x 64d), row stride 144B
  for (int idx = tid; idx < 66 * 8; idx += 256) {
    const int t = idx >> 3, c = idx & 7;
    const int s = s0 - 1 + t;
    bf16x8 val = {0, 0, 0, 0, 0, 0, 0, 0};
    if (s >= 0 && s < S_)
      val = *(const bf16x8*)&qb[((size_t)(b * S_ + s)) * D_ + h * DP_ + c * 8];
    *(bf16x8*)(smem + 32768 + t * 144 + c * 16) = val;
  }
  __syncthreads();

  // ---- phase A ----
  f32x4 acc[4][4];
#pragma unroll
  for (int m = 0; m < 4; ++m)
#pragma unroll
    for (int n = 0; n < 4; ++n) acc[m][n] = (f32x4){0.f, 0.f, 0.f, 0.f};

  const short* Mbh = Mb + (size_t)bh * 3 * R_ * DP_;
#pragma unroll
  for (int i = 0; i < 3; ++i) {
    bf16x8 qf[4][2];
#pragma unroll
    for (int m = 0; m < 4; ++m)
#pragma unroll
      for (int kk = 0; kk < 2; ++kk)
        qf[m][kk] = *(const bf16x8*)(smem + 32768 + (m * 16 + l15 + i) * 144 +
                                     ((kk * 4 + l16) << 4));
    const short* Mi = Mbh + (size_t)i * R_ * DP_;
#pragma unroll
    for (int n = 0; n < 4; ++n) {
      const short* mrow = Mi + (size_t)(w * 64 + n * 16 + l15) * DP_ + l16 * 8;
      const bf16x8 m0 = *(const bf16x8*)mrow;
      const bf16x8 m1 = *(const bf16x8*)(mrow + 32);
#pragma unroll
      for (int m = 0; m < 4; ++m) {
        acc[m][n] = __builtin_amdgcn_mfma_f32_16x16x32_bf16(qf[m][0], m0, acc[m][n], 0, 0, 0);
        acc[m][n] = __builtin_amdgcn_mfma_f32_16x16x32_bf16(qf[m][1], m1, acc[m][n], 0, 0, 0);
      }
    }
  }
#pragma unroll
  for (int m = 0; m < 4; ++m)
#pragma unroll
    for (int n = 0; n < 4; ++n)
#pragma unroll
      for (int rr = 0; rr < 4; ++rr) {
        const int t = m * 16 + l16 * 4 + rr;
        const int c = w * 64 + n * 16 + l15;
        const int off = t * 512 + (((c >> 3) ^ (t & 7)) << 4) + ((c & 7) << 1);
        *(short*)(smem + off) = f2bf(acc[m][n][rr]);
      }
  __syncthreads();

  // ---- phase B: softmax, 4 rows in parallel (16-lane groups) ----
  {
    const int g = l >> 4, u = l & 15;
#pragma unroll
    for (int it = 0; it < 4; ++it) {
      const int t = w * 16 + it * 4 + g;
      const int off0 = t * 512 + (((u * 2) ^ (t & 7)) << 4);
      const int off1 = t * 512 + (((u * 2 + 1) ^ (t & 7)) << 4);
      bf16x8 p0 = *(bf16x8*)(smem + off0);
      bf16x8 p1 = *(bf16x8*)(smem + off1);
      float f[16];
#pragma unroll
      for (int j = 0; j < 8; ++j) { f[j] = bf2f(p0[j]); f[8 + j] = bf2f(p1[j]); }
      float mx = f[0];
#pragma unroll
      for (int j = 1; j < 16; ++j) mx = fmaxf(mx, f[j]);
#pragma unroll
      for (int d = 1; d < 16; d <<= 1) mx = fmaxf(mx, __shfl_xor(mx, d, 64));
      float sm = 0.f;
#pragma unroll
      for (int j = 0; j < 16; ++j) { f[j] = __expf(f[j] - mx); sm += f[j]; }
#pragma unroll
      for (int d = 1; d < 16; d <<= 1) sm += __shfl_xor(sm, d, 64);
      const float inv = 1.f / sm;
#pragma unroll
      for (int j = 0; j < 8; ++j) { p0[j] = f2bf(f[j] * inv); p1[j] = f2bf(f[8 + j] * inv); }
      *(bf16x8*)(smem + off0) = p0;
      *(bf16x8*)(smem + off1) = p1;
    }
  }
  __syncthreads();

  // ---- phase C: PV ----
  f32x4 pacc[4];
#pragma unroll
  for (int n = 0; n < 4; ++n) pacc[n] = (f32x4){0.f, 0.f, 0.f, 0.f};
#pragma unroll
  for (int kk = 0; kk < 8; ++kk) {
    const int row = w * 16 + l15;
    const int ck = kk * 4 + l16;
    const bf16x8 pa = *(const bf16x8*)(smem + row * 512 + ((ck ^ (row & 7)) << 4));
#pragma unroll
    for (int n = 0; n < 4; ++n) {
      const bf16x8 bv = *(const bf16x8*)(vprojTb + ((size_t)bh * DP_ + n * 16 + l15) * R_ +
                                         (kk << 5) + (l16 << 3));
      pacc[n] = __builtin_amdgcn_mfma_f32_16x16x32_bf16(pa, bv, pacc[n], 0, 0, 0);
    }
  }
#pragma unroll
  for (int n = 0; n < 4; ++n)
#pragma unroll
    for (int rr = 0; rr < 4; ++rr) {
      const int s = s0 + w * 16 + l16 * 4 + rr;
      const int d = n * 16 + l15;
      aob[((size_t)(b * S_ + s)) * D_ + h * DP_ + d] = f2bf(pacc[n][rr]);
    }
}

// ============================================================
extern "C" void kernel_launch(void* const* d_in, const int* in_sizes, int n_in,
                              void* d_out, int out_size, void* d_ws, size_t ws_size,
                              hipStream_t stream) {
  const float* x = (const float*)d_in[0];
  const float* wq = (const float*)d_in[1];
  const float* wk = (const float*)d_in[2];
  const float* wv = (const float*)d_in[3];
  const float* E = (const float*)d_in[4];
  const float* F = (const float*)d_in[5];
  const float* ck = (const float*)d_in[6];
  const float* wo = (const float*)d_in[8];
  const float* bo = (const float*)d_in[9];
  float* out = (float*)d_out;

  const size_t QN = (size_t)B_ * S_ * D_;  // 16.78M
  const size_t WN = (size_t)D_ * D_;       // 1.05M
  const size_t PN = (size_t)64 * R_ * DP_; // 1.05M

  short* xb = (short*)d_ws;        // [later ETb, then Mb]
  short* wT = xb + QN;             // 4 weights [N][K] bf16 (q,k,v,o)
  short* qb = wT + 4 * WN;
  short* kTb = qb + QN;            // [bh][d][n]
  short* vTb = kTb + QN;           // [bh][d][n]  [later aob]
  short* FTb = vTb + QN;           // [h][r][n]
  short* kprojTb = FTb + QN;       // [bh][d][r]
  short* vprojTb = kprojTb + PN;   // [bh][d][r]
  short* Tt = vprojTb + PN;        // 3*256*256
  short* ETb = xb;
  short* Mb = xb;
  short* aob = vTb;

  convert_x_kernel<<<2048, 256, 0, stream>>>(x, xb);
  {
    dim3 g(16, 16, 4);
    transpose_w_kernel<<<g, 256, 0, stream>>>(wq, wk, wv, wo, wT);
  }
  qkv_mfma_kernel<<<3072, 256, 0, stream>>>(xb, wT, qb, kTb, vTb);
  build_T_kernel<<<768, 256, 0, stream>>>(ck, Tt);
  {
    dim3 g(S_ / 64, R_ / 64, 32);
    transpose_EF_kernel<<<g, 256, 0, stream>>>(E, F, ETb, FTb);
  }
  {
    dim3 g(2, 64, 2);
    proj_mfma_kernel<<<g, 256, 0, stream>>>(ETb, FTb, kTb, vTb, kprojTb, vprojTb);
  }
  {
    dim3 g(4, 64);
    build_M_kernel<<<g, 256, 0, stream>>>(Tt, kprojTb, Mb);
  }
  {
    dim3 g(S_ / 64, B_ * H_);
    attn_fused_kernel<<<g, 256, 0, stream>>>(qb, Mb, vprojTb, aob);
  }
  out_mfma_kernel<<<1024, 256, 0, stream>>>(aob, wT + 3 * WN, bo, out);
}